// Round 16
// baseline (1721.979 us; speedup 1.0000x reference)
//
#include <hip/hip_runtime.h>
#include <hip/hip_bf16.h>

#define Nn 8192
#define Ne 131072
#define Cc 256
#define Bb 64

typedef __hip_bfloat16 bf16;
typedef __attribute__((ext_vector_type(8))) short bf16x8;
typedef __attribute__((ext_vector_type(4))) float f32x4;

__device__ __forceinline__ float b2f(unsigned short s){
  return __uint_as_float(((unsigned)s) << 16);
}
__device__ __forceinline__ unsigned short f2b(float v){
  bf16 h = __float2bfloat16(v);
  return *(unsigned short*)&h;
}

__device__ __forceinline__ void block_reduce_2(float& s1, float& s2, float* sm){
#pragma unroll
  for (int off = 32; off > 0; off >>= 1){
    s1 += __shfl_down(s1, off, 64);
    s2 += __shfl_down(s2, off, 64);
  }
  int lane = threadIdx.x & 63;
  int wid  = threadIdx.x >> 6;
  if (lane == 0){ sm[wid] = s1; sm[4 + wid] = s2; }
  __syncthreads();
  s1 = sm[0] + sm[1] + sm[2] + sm[3];
  s2 = sm[4] + sm[5] + sm[6] + sm[7];
}

// ================= mg_k: bf16 MFMA GEMM, K=256, contiguous A =================
// gelAux: if non-null, epilogue v = (acc+bias) * gelu_exact(aux[row,col]).
__global__ __launch_bounds__(256) void mg_k(
  const bf16* __restrict__ A,
  const bf16* __restrict__ Bpack, const float* __restrict__ bias,
  bf16* __restrict__ o0, bf16* __restrict__ o1, bf16* __restrict__ o2,
  bf16* __restrict__ o3, bf16* __restrict__ o4,
  float* __restrict__ fout, bf16* __restrict__ foutBf,
  int actMode, const int* __restrict__ outPerm,
  const bf16* __restrict__ gelAux)
{
  int lane = threadIdx.x & 63;
  int wave = threadIdx.x >> 6;
  int panel = blockIdx.x;
  long m0 = (long)blockIdx.y * 64;
  int row16 = lane & 15;
  int kg    = lane >> 4;

  const bf16* a0 = A + (m0 + row16) * 256 + kg * 8;
  const bf16* bp = Bpack + (size_t)panel * 65536;

  f32x4 acc[4][4];
#pragma unroll
  for (int i = 0; i < 4; i++)
#pragma unroll
    for (int j = 0; j < 4; j++) acc[i][j] = (f32x4){0.f, 0.f, 0.f, 0.f};

#pragma unroll
  for (int c8 = 0; c8 < 8; c8++){
    bf16x8 a[4], b[4];
#pragma unroll
    for (int im = 0; im < 4; im++)
      a[im] = *(const bf16x8*)(a0 + im * 4096 + c8 * 32);
#pragma unroll
    for (int in = 0; in < 4; in++)
      b[in] = *(const bf16x8*)(bp + ((size_t)((c8 * 16 + wave * 4 + in) * 64 + lane)) * 8);
#pragma unroll
    for (int im = 0; im < 4; im++)
#pragma unroll
      for (int in = 0; in < 4; in++)
        acc[im][in] = __builtin_amdgcn_mfma_f32_16x16x32_bf16(
                        a[im], b[in], acc[im][in], 0, 0, 0);
  }

  int colq = lane & 15;
  int quad = lane >> 4;

  if (fout){
#pragma unroll
    for (int im = 0; im < 4; im++)
#pragma unroll
      for (int in = 0; in < 4; in++){
        int col = wave * 64 + in * 16 + colq;
        float bv = bias ? bias[col] : 0.f;
#pragma unroll
        for (int r = 0; r < 4; r++){
          long row = m0 + im * 16 + quad * 4 + r;
          float v = acc[im][in][r] + bv + fout[row * 256 + col];
          fout[row * 256 + col] = v;
          if (foutBf) foutBf[row * 256 + col] = __float2bfloat16(v);
        }
      }
    return;
  }

  bf16* op = (panel == 0) ? o0 : (panel == 1) ? o1 : (panel == 2) ? o2
           : (panel == 3) ? o3 : o4;
#pragma unroll
  for (int im = 0; im < 4; im++){
    long orow[4];
#pragma unroll
    for (int r = 0; r < 4; r++){
      long row = m0 + im * 16 + quad * 4 + r;
      orow[r] = outPerm ? (long)outPerm[row] : row;
    }
#pragma unroll
    for (int in = 0; in < 4; in++){
      int col = wave * 64 + in * 16 + colq;
      float bv = bias ? bias[panel * 256 + col] : 0.f;
#pragma unroll
      for (int r = 0; r < 4; r++){
        long row = m0 + im * 16 + quad * 4 + r;
        float v = acc[im][in][r] + bv;
        if (actMode == 1) v = v / (1.f + __expf(-v));
        if (gelAux){
          float xg = b2f(((const unsigned short*)gelAux)[row * 256 + col]);
          v *= 0.5f * xg * (1.0f + erff(xg * 0.70710678118654752f));
        }
        op[orow[r] * 256 + col] = __float2bfloat16(v);
      }
    }
  }
}

// ================= rbf_mg_k: e_in = silu(rbf(d(ea)) @ W + b) ================
// d computed in-kernel from edge_attr (3 floats/row).
__global__ __launch_bounds__(256) void rbf_mg_k(
  const float* __restrict__ ea,
  const bf16* __restrict__ Bpack, const float* __restrict__ bias,
  bf16* __restrict__ out, const int* __restrict__ outPerm)
{
  int lane = threadIdx.x & 63;
  int wave = threadIdx.x >> 6;
  long m0 = (long)blockIdx.x * 64;
  int row16 = lane & 15;
  int kg    = lane >> 4;

  float dv[4];
#pragma unroll
  for (int im = 0; im < 4; im++){
    long r = m0 + row16 + im * 16;
    float a = ea[r * 3 + 0], b = ea[r * 3 + 1], c = ea[r * 3 + 2];
    dv[im] = -rsqrtf(a * a + b * b + c * c);
  }

  f32x4 acc[4][4];
#pragma unroll
  for (int i = 0; i < 4; i++)
#pragma unroll
    for (int j = 0; j < 4; j++) acc[i][j] = (f32x4){0.f, 0.f, 0.f, 0.f};

#pragma unroll
  for (int c8 = 0; c8 < 8; c8++){
    bf16x8 a[4], b[4];
#pragma unroll
    for (int im = 0; im < 4; im++){
#pragma unroll
      for (int j = 0; j < 8; j++){
        int k = c8 * 32 + kg * 8 + j;
        float cen = -6.0f + (float)k * (6.0f / 255.0f);
        float df  = dv[im] - cen;
        a[im][j] = (short)f2b(__expf(-42.5f * df * df));
      }
    }
#pragma unroll
    for (int in = 0; in < 4; in++)
      b[in] = *(const bf16x8*)(Bpack + ((size_t)((c8 * 16 + wave * 4 + in) * 64 + lane)) * 8);
#pragma unroll
    for (int im = 0; im < 4; im++)
#pragma unroll
      for (int in = 0; in < 4; in++)
        acc[im][in] = __builtin_amdgcn_mfma_f32_16x16x32_bf16(
                        a[im], b[in], acc[im][in], 0, 0, 0);
  }

  int colq = lane & 15;
  int quad = lane >> 4;
#pragma unroll
  for (int im = 0; im < 4; im++){
    long orow[4];
#pragma unroll
    for (int r = 0; r < 4; r++){
      long row = m0 + im * 16 + quad * 4 + r;
      orow[r] = outPerm ? (long)outPerm[row] : row;
    }
#pragma unroll
    for (int in = 0; in < 4; in++){
      int col = wave * 64 + in * 16 + colq;
      float bv = bias[col];
#pragma unroll
      for (int r = 0; r < 4; r++){
        float v = acc[im][in][r] + bv;
        v = v / (1.f + __expf(-v));     // silu
        out[orow[r] * 256 + col] = __float2bfloat16(v);
      }
    }
  }
}

// ================= conv_edge_k: fused edge pipeline + segment-sum ============
__global__ __launch_bounds__(256) void conv_edge_k(
  const bf16* __restrict__ e_in,
  const bf16* __restrict__ Bedge, const float* __restrict__ bedge,
  const bf16* __restrict__ Bm, const float* __restrict__ bm,
  const bf16* __restrict__ q,
  const bf16* __restrict__ kp1, const bf16* __restrict__ kp2,
  const bf16* __restrict__ vp1, const bf16* __restrict__ vp2,
  const int* __restrict__ dstS, const int* __restrict__ srcS,
  const float* __restrict__ lg, const float* __restrict__ lb,
  float* __restrict__ aggS)
{
  __shared__ bf16 eK[32 * 256];   // 16 KB
  __shared__ bf16 eM[32 * 256];   // 16 KB
  __shared__ int  sdst[32];
  int lane = threadIdx.x & 63;
  int wave = threadIdx.x >> 6;
  long m0 = (long)blockIdx.x * 32;
  int row16 = lane & 15;
  int kg    = lane >> 4;
  int colq  = row16;
  int quad  = kg;

  if (threadIdx.x < 32) sdst[threadIdx.x] = dstS[m0 + threadIdx.x];

  int drs[8], srs[8];
#pragma unroll
  for (int it = 0; it < 8; it++){
    drs[it] = dstS[m0 + it * 4 + wave];
    srs[it] = srcS[m0 + it * 4 + wave];
  }
  int c0g = lane * 4;
  ushort4 k1 = *(const ushort4*)((const unsigned short*)kp1 + (long)drs[0] * 256 + c0g);
  ushort4 k2 = *(const ushort4*)((const unsigned short*)kp2 + (long)srs[0] * 256 + c0g);
  ushort4 qv = *(const ushort4*)((const unsigned short*)q   + (long)drs[0] * 256 + c0g);
  ushort4 v1 = *(const ushort4*)((const unsigned short*)vp1 + (long)drs[0] * 256 + c0g);
  ushort4 v2 = *(const ushort4*)((const unsigned short*)vp2 + (long)srs[0] * 256 + c0g);

  const bf16* a0 = e_in + (m0 + row16) * 256 + kg * 8;

  for (int p = 0; p < 2; p++){
    const bf16* bp = Bedge + (size_t)p * 65536;
    f32x4 acc[2][4];
#pragma unroll
    for (int i = 0; i < 2; i++)
#pragma unroll
      for (int j = 0; j < 4; j++) acc[i][j] = (f32x4){0.f, 0.f, 0.f, 0.f};
#pragma unroll
    for (int c8 = 0; c8 < 8; c8++){
      bf16x8 a[2], b[4];
#pragma unroll
      for (int im = 0; im < 2; im++)
        a[im] = *(const bf16x8*)(a0 + im * 4096 + c8 * 32);
#pragma unroll
      for (int in = 0; in < 4; in++)
        b[in] = *(const bf16x8*)(bp + ((size_t)((c8 * 16 + wave * 4 + in) * 64 + lane)) * 8);
#pragma unroll
      for (int im = 0; im < 2; im++)
#pragma unroll
        for (int in = 0; in < 4; in++)
          acc[im][in] = __builtin_amdgcn_mfma_f32_16x16x32_bf16(
                          a[im], b[in], acc[im][in], 0, 0, 0);
    }
    bf16* E = p ? eM : eK;
    const float* bb = bedge + p * 256;
#pragma unroll
    for (int im = 0; im < 2; im++)
#pragma unroll
      for (int in = 0; in < 4; in++){
        int col = wave * 64 + in * 16 + colq;
        float bv = bb[col];
#pragma unroll
        for (int r = 0; r < 4; r++){
          int row = im * 16 + quad * 4 + r;
          int idx = row * 256 + ((((col >> 3) ^ (row & 7))) << 3) + (col & 7);
          E[idx] = __float2bfloat16(acc[im][in][r] + bv);
        }
      }
  }
  __syncthreads();

  // gate
  {
    int cb = lane >> 1;
    int e0 = (lane & 1) * 4;
    float4 gv = *(const float4*)(lg + c0g);
    float4 bv = *(const float4*)(lb + c0g);
#pragma unroll
    for (int it = 0; it < 8; it++){
      int row = it * 4 + wave;
      int li = row * 256 + ((cb ^ (row & 7)) << 3) + e0;
      ushort4 ek = *(const ushort4*)((const unsigned short*)eK + li);
      ushort4 em = *(const ushort4*)((const unsigned short*)eM + li);
      ushort4 nk1, nk2, nqv, nv1, nv2;
      if (it < 7){
        long dr2 = drs[it + 1], sr2 = srs[it + 1];
        nk1 = *(const ushort4*)((const unsigned short*)kp1 + dr2 * 256 + c0g);
        nk2 = *(const ushort4*)((const unsigned short*)kp2 + sr2 * 256 + c0g);
        nqv = *(const ushort4*)((const unsigned short*)q   + dr2 * 256 + c0g);
        nv1 = *(const ushort4*)((const unsigned short*)vp1 + dr2 * 256 + c0g);
        nv2 = *(const ushort4*)((const unsigned short*)vp2 + sr2 * 256 + c0g);
      }
      float a0g = (b2f(ek.x) + b2f(k1.x) + b2f(k2.x)) * b2f(qv.x) * 0.0625f;
      float a1g = (b2f(ek.y) + b2f(k1.y) + b2f(k2.y)) * b2f(qv.y) * 0.0625f;
      float a2g = (b2f(ek.z) + b2f(k1.z) + b2f(k2.z)) * b2f(qv.z) * 0.0625f;
      float a3g = (b2f(ek.w) + b2f(k1.w) + b2f(k2.w)) * b2f(qv.w) * 0.0625f;
      float s1 = a0g + a1g + a2g + a3g;
      float s2 = a0g*a0g + a1g*a1g + a2g*a2g + a3g*a3g;
#pragma unroll
      for (int off = 1; off < 64; off <<= 1){
        s1 += __shfl_xor(s1, off, 64);
        s2 += __shfl_xor(s2, off, 64);
      }
      float mn  = s1 * (1.0f / Cc);
      float var = s2 * (1.0f / Cc) - mn * mn;
      float rs  = rsqrtf(var + 1e-5f);
      float g0 = 1.f / (1.f + __expf(-((a0g - mn) * rs * gv.x + bv.x)));
      float g1 = 1.f / (1.f + __expf(-((a1g - mn) * rs * gv.y + bv.y)));
      float g2 = 1.f / (1.f + __expf(-((a2g - mn) * rs * gv.z + bv.z)));
      float g3 = 1.f / (1.f + __expf(-((a3g - mn) * rs * gv.w + bv.w)));
      ushort4 o;
      o.x = f2b((b2f(em.x) + b2f(v1.x) + b2f(v2.x)) * g0);
      o.y = f2b((b2f(em.y) + b2f(v1.y) + b2f(v2.y)) * g1);
      o.z = f2b((b2f(em.z) + b2f(v1.z) + b2f(v2.z)) * g2);
      o.w = f2b((b2f(em.w) + b2f(v1.w) + b2f(v2.w)) * g3);
      *(ushort4*)((unsigned short*)eK + li) = o;
      k1 = nk1; k2 = nk2; qv = nqv; v1 = nv1; v2 = nv2;
    }
  }
  __syncthreads();

  // msg @ Wm
  f32x4 acc[2][4];
#pragma unroll
  for (int i = 0; i < 2; i++)
#pragma unroll
    for (int j = 0; j < 4; j++) acc[i][j] = (f32x4){0.f, 0.f, 0.f, 0.f};
  int r7 = row16 & 7;
#pragma unroll
  for (int c8 = 0; c8 < 8; c8++){
    bf16x8 a[2], b[4];
#pragma unroll
    for (int im = 0; im < 2; im++)
      a[im] = *(const bf16x8*)&eK[(row16 + im * 16) * 256 + (((c8 * 4 + kg) ^ r7) << 3)];
#pragma unroll
    for (int in = 0; in < 4; in++)
      b[in] = *(const bf16x8*)(Bm + ((size_t)((c8 * 16 + wave * 4 + in) * 64 + lane)) * 8);
#pragma unroll
    for (int im = 0; im < 2; im++)
#pragma unroll
      for (int in = 0; in < 4; in++)
        acc[im][in] = __builtin_amdgcn_mfma_f32_16x16x32_bf16(
                        a[im], b[in], acc[im][in], 0, 0, 0);
  }

  // row LN -> eM
  float s1a[2][4], s2a[2][4];
#pragma unroll
  for (int im = 0; im < 2; im++)
#pragma unroll
    for (int r = 0; r < 4; r++){
      float t1 = 0.f, t2 = 0.f;
#pragma unroll
      for (int in = 0; in < 4; in++){
        int col = wave * 64 + in * 16 + colq;
        float v = acc[im][in][r] + bm[col];
        t1 += v; t2 += v * v;
      }
#pragma unroll
      for (int off = 1; off < 16; off <<= 1){
        t1 += __shfl_xor(t1, off, 64);
        t2 += __shfl_xor(t2, off, 64);
      }
      s1a[im][r] = t1; s2a[im][r] = t2;
    }
  __syncthreads();
  float* red = (float*)eK;
  if (colq < 8){
    int imw = colq >> 2, rw = colq & 3;
    int rr = imw * 16 + quad * 4 + rw;
    red[(wave * 32 + rr) * 2 + 0] = s1a[imw][rw];
    red[(wave * 32 + rr) * 2 + 1] = s2a[imw][rw];
  }
  __syncthreads();
#pragma unroll
  for (int im = 0; im < 2; im++)
#pragma unroll
    for (int r = 0; r < 4; r++){
      int row = im * 16 + quad * 4 + r;
      float ts1 = red[row * 2]           + red[(32 + row) * 2]
                + red[(64 + row) * 2]    + red[(96 + row) * 2];
      float ts2 = red[row * 2 + 1]       + red[(32 + row) * 2 + 1]
                + red[(64 + row) * 2 + 1] + red[(96 + row) * 2 + 1];
      float mn  = ts1 * (1.0f / Cc);
      float var = ts2 * (1.0f / Cc) - mn * mn;
      float rs  = rsqrtf(var + 1e-5f);
#pragma unroll
      for (int in = 0; in < 4; in++){
        int col = wave * 64 + in * 16 + colq;
        float v = acc[im][in][r] + bm[col];
        ((unsigned short*)eM)[row * 256 + col] = f2b((v - mn) * rs);
      }
    }
  __syncthreads();

  // segment-sum over dst runs
  {
    int t = threadIdx.x;
    float sum = 0.f;
    int cur = sdst[0];
    for (int r = 0; r < 32; r++){
      int d = sdst[r];
      if (d != cur){
        atomicAdd(&aggS[(long)cur * 256 + t], sum);
        sum = 0.f; cur = d;
      }
      sum += b2f(((const unsigned short*)eM)[r * 256 + t]);
    }
    atomicAdd(&aggS[(long)cur * 256 + t], sum);
  }
}

// ---------------- pack fp32 W[k][panel*256+n] -> bf16 fragment layout --------
__global__ __launch_bounds__(256) void pack_b2_k(
  const float* __restrict__ W, int ldW, bf16* __restrict__ out)
{
  int panel = blockIdx.y;
  long p = (long)blockIdx.x * 256 + threadIdx.x;
  int j    = p & 7;
  int lane = (p >> 3) & 63;
  int nt   = (p >> 9) & 15;
  int kc   = p >> 13;
  int k = kc * 32 + (lane >> 4) * 8 + j;
  int n = nt * 16 + (lane & 15);
  out[(size_t)panel * 65536 + p] =
    __float2bfloat16(W[(long)k * ldW + panel * 256 + n]);
}

// batched pack
__global__ __launch_bounds__(256) void pack_qm_k(
  const float* __restrict__ Wq, const float* __restrict__ Wm,
  bf16* __restrict__ N5, bf16* __restrict__ WpM)
{
  int z = blockIdx.y;
  const float* W; bf16* out;
  if (z < 3){ W = Wq + (size_t)z * 65536; out = N5 + (size_t)z * 327680; }
  else      { W = Wm + (size_t)(z-3) * 65536; out = WpM + (size_t)(z-3) * 65536; }
  long p = (long)blockIdx.x * 256 + threadIdx.x;
  int j    = p & 7;
  int lane = (p >> 3) & 63;
  int nt   = (p >> 9) & 15;
  int kc   = p >> 13;
  int k = kc * 32 + (lane >> 4) * 8 + j;
  int n = nt * 16 + (lane & 15);
  out[p] = __float2bfloat16(W[(long)k * 256 + n]);
}

// ================= fold_k: batched 256x256x256 fp32 GEMM -> packed bf16 ======
__global__ __launch_bounds__(256) void fold_k(
  const float* __restrict__ Wk, const float* __restrict__ Wv,
  const float* __restrict__ We,
  const float* __restrict__ Wku, const float* __restrict__ Wmu,
  bf16* __restrict__ N5, bf16* __restrict__ EG)
{
  int z = blockIdx.z, i = z / 6, j = z % 6;
  const float* A; const float* B; bf16* C;
  if (j < 2){
    A = Wk + (size_t)i * 65536; B = Wku + (size_t)i * 196608 + j * 65536;
    C = N5 + (size_t)i * 327680 + (size_t)(1 + j) * 65536;
  } else if (j < 4){
    A = Wv + (size_t)i * 65536; B = Wmu + (size_t)i * 196608 + (j - 2) * 65536;
    C = N5 + (size_t)i * 327680 + (size_t)(3 + (j - 2)) * 65536;
  } else {
    A = We + (size_t)i * 65536;
    B = (j == 4 ? Wku : Wmu) + (size_t)i * 196608 + 131072;
    C = EG + (size_t)i * 131072 + (size_t)(j - 4) * 65536;
  }

  __shared__ __align__(16) float As[16][64];
  __shared__ __align__(16) float Bs[16][128];
  int t = threadIdx.x;
  int m0 = blockIdx.x * 64;
  int n0 = blockIdx.y * 128;

  float acc[4][8];
#pragma unroll
  for (int a = 0; a < 4; a++)
#pragma unroll
    for (int b = 0; b < 8; b++) acc[a][b] = 0.f;
  int tm = t >> 4, tn = t & 15, mA = t & 63, kgA = t >> 6;

  for (int k0 = 0; k0 < 256; k0 += 16){
#pragma unroll
    for (int it = 0; it < 4; it++){
      int kl = kgA + it * 4;
      As[kl][mA] = A[(long)(m0 + mA) * 256 + k0 + kl];
    }
#pragma unroll
    for (int it = 0; it < 8; it++){
      int idx = t + it * 256;
      int kl = idx >> 7, n = idx & 127;
      Bs[kl][n] = B[(long)(k0 + kl) * 256 + n0 + n];
    }
    __syncthreads();
#pragma unroll
    for (int kk = 0; kk < 16; kk++){
      float4 a  = *(const float4*)&As[kk][tm * 4];
      float4 b0 = *(const float4*)&Bs[kk][tn * 4];
      float4 b1 = *(const float4*)&Bs[kk][64 + tn * 4];
      float av[4] = {a.x, a.y, a.z, a.w};
      float bv[8] = {b0.x, b0.y, b0.z, b0.w, b1.x, b1.y, b1.z, b1.w};
#pragma unroll
      for (int ii = 0; ii < 4; ii++)
#pragma unroll
        for (int jj = 0; jj < 8; jj++)
          acc[ii][jj] = __builtin_fmaf(av[ii], bv[jj], acc[ii][jj]);
    }
    __syncthreads();
  }
#pragma unroll
  for (int ii = 0; ii < 4; ii++){
    int m = m0 + tm * 4 + ii;
#pragma unroll
    for (int h = 0; h < 2; h++){
#pragma unroll
      for (int jj = 0; jj < 4; jj++){
        int n = n0 + h * 64 + tn * 4 + jj;
        int kc = m >> 5, nt = n >> 4;
        int ln_ = ((m >> 3) & 3) * 16 + (n & 15);
        long idx = ((long)(kc * 16 + nt) * 64 + ln_) * 8 + (m & 7);
        C[idx] = __float2bfloat16(acc[ii][h * 4 + jj]);
      }
    }
  }
}

// ================= generic fp32 tiled GEMM (embeddings / head) ==============
__global__ __launch_bounds__(256) void gemm_k(
  const void* __restrict__ A0, int K0, int ld0,
  long M, int Nout,
  const float* __restrict__ W, const float* __restrict__ bias,
  const float* __restrict__ res, int ldRes,
  void* __restrict__ Cout, int outDt, int actMode)
{
  __shared__ __align__(16) float As[16][64];
  __shared__ __align__(16) float Bs[16][128];

  int t = threadIdx.x;
  long m0 = (long)blockIdx.x * 64;
  int  n0 = blockIdx.y * 128;

  float acc[4][8];
#pragma unroll
  for (int i = 0; i < 4; i++)
#pragma unroll
    for (int j = 0; j < 8; j++) acc[i][j] = 0.f;

  int tm = t >> 4, tn = t & 15, mA = t & 63, kgA = t >> 6;
  long rowA = m0 + mA;
  bool rv = rowA < M;

  for (int k0 = 0; k0 < K0; k0 += 16){
#pragma unroll
    for (int it = 0; it < 4; it++){
      int kl = kgA + it * 4;
      int k  = k0 + kl;
      float v = 0.f;
      if (rv && k < K0) v = ((const float*)A0)[rowA * (long)ld0 + k];
      As[kl][mA] = v;
    }
#pragma unroll
    for (int it = 0; it < 8; it++){
      int idx = t + it * 256;
      int kl = idx >> 7, n = idx & 127;
      int k  = k0 + kl;
      Bs[kl][n] = (k < K0) ? W[(long)k * Nout + n0 + n] : 0.f;
    }
    __syncthreads();
#pragma unroll
    for (int kk = 0; kk < 16; kk++){
      float4 a  = *(const float4*)&As[kk][tm * 4];
      float4 b0 = *(const float4*)&Bs[kk][tn * 4];
      float4 b1 = *(const float4*)&Bs[kk][64 + tn * 4];
      float av[4] = {a.x, a.y, a.z, a.w};
      float bv[8] = {b0.x, b0.y, b0.z, b0.w, b1.x, b1.y, b1.z, b1.w};
#pragma unroll
      for (int i = 0; i < 4; i++)
#pragma unroll
        for (int j = 0; j < 8; j++)
          acc[i][j] = __builtin_fmaf(av[i], bv[j], acc[i][j]);
    }
    __syncthreads();
  }

#pragma unroll
  for (int i = 0; i < 4; i++){
    long m = m0 + tm * 4 + i;
    if (m >= M) continue;
#pragma unroll
    for (int h = 0; h < 2; h++){
      int nb = n0 + h * 64 + tn * 4;
      float po[4];
#pragma unroll
      for (int j = 0; j < 4; j++){
        float v = acc[i][h * 4 + j];
        if (bias) v += bias[nb + j];
        if (actMode == 1) v = v / (1.0f + __expf(-v));
        if (res) v += res[m * (long)ldRes + nb + j];
        po[j] = v;
      }
      if (outDt){
        __align__(8) unsigned short tb[4];
#pragma unroll
        for (int j = 0; j < 4; j++) tb[j] = f2b(po[j]);
        *(short4*)((bf16*)Cout + m * (long)Nout + nb) = *(short4*)tb;
      } else {
        float4 ov = {po[0], po[1], po[2], po[3]};
        *(float4*)((float*)Cout + m * (long)Nout + nb) = ov;
      }
    }
  }
}

// ---------------- utility ----------------
__global__ __launch_bounds__(256) void zero2_k(float* __restrict__ a, long na,
                                               float* __restrict__ b2, long nb){
  long i = (long)blockIdx.x * 256 + threadIdx.x;
  long stride = (long)gridDim.x * 256;
  for (long j = i; j < na; j += stride) a[j] = 0.f;
  for (long j = i; j < nb; j += stride) b2[j] = 0.f;
}
__global__ __launch_bounds__(256) void zero_i_k(int* __restrict__ p, long n){
  long i = (long)blockIdx.x * 256 + threadIdx.x;
  long stride = (long)gridDim.x * 256;
  for (; i < n; i += stride) p[i] = 0;
}
__global__ __launch_bounds__(256) void f2bf_k(bf16* __restrict__ d,
                                              const float* __restrict__ s, long n){
  long i = (long)blockIdx.x * 256 + threadIdx.x;
  long stride = (long)gridDim.x * 256;
  for (; i < n; i += stride) d[i] = __float2bfloat16(s[i]);
}

// batched bias fold: z = i*2+kind
__global__ __launch_bounds__(256) void fuse_bias_all_k(
  const float* __restrict__ bku, const float* __restrict__ bmu,
  const float* __restrict__ be,
  const float* __restrict__ bk, const float* __restrict__ bv,
  const float* __restrict__ Wku, const float* __restrict__ Wmu,
  float* __restrict__ b_edge)
{
  int z = blockIdx.x, i = z >> 1, kind = z & 1;
  const float* W  = (kind ? Wmu : Wku) + (size_t)i * 196608;
  const float* b0 = (kind ? bmu : bku) + i * 256;
  const float* vb = (kind ? bv : bk) + i * 256;
  const float* eb = be + i * 256;
  int n = threadIdx.x;
  float s = b0[n];
  for (int k = 0; k < Cc; k++){
    s += eb[k] * W[(512 + k) * 256 + n];
    s += vb[k] * (W[k * 256 + n] + W[(256 + k) * 256 + n]);
  }
  b_edge[i * 512 + kind * 256 + n] = s;
}

// node5 bias for all layers
__global__ __launch_bounds__(256) void nodeb_all_k(const float* __restrict__ bq,
                                                   float* __restrict__ out){
  int z = blockIdx.x, i = z / 5, p = z % 5;
  out[i * 1280 + p * 256 + threadIdx.x] = (p == 0) ? bq[i * 256 + threadIdx.x] : 0.f;
}

// ---------------- segment sort ----------------
__global__ __launch_bounds__(256) void hist_k(const int* __restrict__ dst,
                                              int* __restrict__ hist)
{
  int e = blockIdx.x * 256 + threadIdx.x;
  if (e < Ne) atomicAdd(&hist[dst[e]], 1);
}

__global__ __launch_bounds__(1024) void scan_k(
  const int* __restrict__ hist, int* __restrict__ rowptr, int* __restrict__ counter)
{
  __shared__ int part[1024];
  int t = threadIdx.x;
  int base = t * 8;
  int local[8];
  int s = 0;
#pragma unroll
  for (int i = 0; i < 8; i++){ local[i] = s; s += hist[base + i]; }
  part[t] = s;
  __syncthreads();
  for (int off = 1; off < 1024; off <<= 1){
    int v = (t >= off) ? part[t - off] : 0;
    __syncthreads();
    part[t] += v;
    __syncthreads();
  }
  int pre = (t == 0) ? 0 : part[t - 1];
#pragma unroll
  for (int i = 0; i < 8; i++){
    int rp = pre + local[i];
    rowptr[base + i] = rp;
    counter[base + i] = rp;
  }
  if (t == 1023) rowptr[8192] = part[1023];
}

__global__ __launch_bounds__(256) void perm_k(const int* __restrict__ dst,
                                              int* __restrict__ counter,
                                              int* __restrict__ pos)
{
  int e = blockIdx.x * 256 + threadIdx.x;
  if (e < Ne) pos[e] = atomicAdd(&counter[dst[e]], 1);
}

__global__ __launch_bounds__(256) void sortidx_k(
  const int* __restrict__ dst, const int* __restrict__ srcI,
  const int* __restrict__ pos, int* __restrict__ dstS, int* __restrict__ srcS)
{
  int e = blockIdx.x * 256 + threadIdx.x;
  if (e < Ne){
    int p = pos[e];
    dstS[p] = dst[e];
    srcS[p] = srcI[e];
  }
}

// ---------------- BatchNorm over y[n][c] = lg[c]*S[n][c] + cnt[n]*lb[c] ------
__global__ __launch_bounds__(256) void bn_stats_f(
  const float* __restrict__ S, const int* __restrict__ rowptr,
  const float* __restrict__ lg, const float* __restrict__ lb,
  float* __restrict__ sums)
{
  int c  = threadIdx.x;
  int r0 = blockIdx.x * 128;
  float gc = lg[c], bc = lb[c];
  float s1 = 0.f, s2 = 0.f;
  for (int r = r0; r < r0 + 128; r++){
    float cnt = (float)(rowptr[r + 1] - rowptr[r]);
    float y = gc * S[(long)r * Cc + c] + cnt * bc;
    s1 += y; s2 += y * y;
  }
  atomicAdd(&sums[c],      s1);
  atomicAdd(&sums[Cc + c], s2);
}

// layer 2 (no pddc): x = softplus(x + BN(y))
__global__ __launch_bounds__(256) void bn_apply_softplus_f(
  float* __restrict__ x, bf16* __restrict__ xbf,
  const float* __restrict__ S, const int* __restrict__ rowptr,
  const float* __restrict__ lg, const float* __restrict__ lb,
  const float* __restrict__ sums,
  const float* __restrict__ g, const float* __restrict__ b)
{
  long r = blockIdx.x;
  int c = threadIdx.x;
  float cnt = (float)(rowptr[r + 1] - rowptr[r]);
  float y = lg[c] * S[r * Cc + c] + cnt * lb[c];
  float m    = sums[c] * (1.0f / Nn);
  float var  = sums[Cc + c] * (1.0f / Nn) - m * m;
  float rstd = rsqrtf(var + 1e-5f);
  float bn = (y - m) * rstd * g[c] + b[c];
  float v  = x[r * Cc + c] + bn;
  float sp = (v > 0.f) ? v + log1pf(__expf(-v)) : log1pf(__expf(v));
  x[r * Cc + c] = sp;
  xbf[r * Cc + c] = __float2bfloat16(sp);
}

// layers 0-1: fused apply + p += sp + p-stats -> sums2
__global__ __launch_bounds__(256) void bn_apply_padd_k(
  float* __restrict__ x, bf16* __restrict__ xbf, float* __restrict__ p,
  const float* __restrict__ S, const int* __restrict__ rowptr,
  const float* __restrict__ lg, const float* __restrict__ lb,
  const float* __restrict__ sums,
  const float* __restrict__ g, const float* __restrict__ b,
  float* __restrict__ sums2)
{
  int c  = threadIdx.x;
  int r0 = blockIdx.x * 128;
  float gc = lg[c], bc = lb[c];
  float m    = sums[c] * (1.0f / Nn);
  float var  = sums[Cc + c] * (1.0f / Nn) - m * m;
  float rstd = rsqrtf(var + 1e-5f);
  float bg = g[c], bb2 = b[c];
  float s1 = 0.f, s2 = 0.f;
  for (int r = r0; r < r0 + 128; r++){
    long idx = (long)r * Cc + c;
    float cnt = (float)(rowptr[r + 1] - rowptr[r]);
    float y = gc * S[idx] + cnt * bc;
    float bn = (y - m) * rstd * bg + bb2;
    float v  = x[idx] + bn;
    float sp = (v > 0.f) ? v + log1pf(__expf(-v)) : log1pf(__expf(v));
    x[idx] = sp;
    xbf[idx] = __float2bfloat16(sp);
    float pv = p[idx] + sp;
    p[idx] = pv;
    s1 += pv; s2 += pv * pv;
  }
  atomicAdd(&sums2[c],      s1);
  atomicAdd(&sums2[Cc + c], s2);
}

// adj_bf = bf16(p*S + T), S/T computed inline from sums2
__global__ __launch_bounds__(256) void bnaff_st_k(
  const float* __restrict__ p, const float* __restrict__ sums,
  const float* __restrict__ g, const float* __restrict__ b,
  bf16* __restrict__ out)
{
  long r = blockIdx.x;
  int c = threadIdx.x;
  float m    = sums[c] * (1.0f / Nn);
  float var  = sums[Cc + c] * (1.0f / Nn) - m * m;
  float rstd = rsqrtf(var + 1e-5f);
  float S = g[c] * rstd;
  float T = b[c] - m * rstd * g[c];
  out[r * 256 + c] = __float2bfloat16(p[r * 256 + c] * S + T);
}

__global__ __launch_bounds__(256) void pool_k(
  const float* __restrict__ x, const int* __restrict__ batch,
  float* __restrict__ pooled, float* __restrict__ counts)
{
  long r = blockIdx.x;
  int c = threadIdx.x;
  long b = batch[r];
  atomicAdd(&pooled[b * Cc + c], x[r * Cc + c]);
  if (c == 0) atomicAdd(&counts[b], 1.0f);
}

__global__ __launch_bounds__(256) void pooldiv_k(
  float* __restrict__ pooled, const float* __restrict__ counts)
{
  int b = blockIdx.x;
  int c = threadIdx.x;
  float cnt = counts[b];
  if (cnt < 1.f) cnt = 1.f;
  pooled[b * Cc + c] /= cnt;
}

__global__ __launch_bounds__(256) void out_k(
  const float* __restrict__ cf, const float* __restrict__ ow,
  const float* __restrict__ ob, float* __restrict__ out)
{
  __shared__ float sm[8];
  int b = blockIdx.x;
  int c = threadIdx.x;
  float v = cf[(long)b * Cc + c] * ow[c];
  float dummy = 0.f;
  block_reduce_2(v, dummy, sm);
  if (c == 0) out[b] = v + ob[0];
}

// ---------------- host helpers ----------------
static inline void launch_gemm(hipStream_t st,
  const void* A0, int K0, int ld0,
  long M, int Nout, const float* W, const float* bias,
  const float* res, int ldRes, void* Cout, int outDt, int act)
{
  dim3 grid((unsigned)((M + 63) / 64), (unsigned)(Nout / 128));
  gemm_k<<<grid, dim3(256), 0, st>>>(
    A0, K0, ld0, M, Nout, W, bias, res, ldRes, Cout, outDt, act);
}

static inline void launch_mg(hipStream_t st, long M, int panels,
  const bf16* A, const bf16* Bpack, const float* bias,
  bf16* o0, bf16* o1, bf16* o2, bf16* o3, bf16* o4,
  float* fout, bf16* foutBf, int act, const int* outPerm,
  const bf16* gelAux = nullptr)
{
  dim3 grid((unsigned)panels, (unsigned)(M / 64));
  mg_k<<<grid, dim3(256), 0, st>>>(A, Bpack, bias, o0, o1, o2, o3, o4,
                                   fout, foutBf, act, outPerm, gelAux);
}

extern "C" void kernel_launch(void* const* d_in, const int* in_sizes, int n_in,
                              void* d_out, int out_size, void* d_ws, size_t ws_size,
                              hipStream_t stream)
{
  (void)in_sizes; (void)n_in; (void)out_size; (void)ws_size;

  const float* node       = (const float*)d_in[0];
  const int*   edge_index = (const int*)  d_in[1];
  const float* edge_attr  = (const float*)d_in[2];
  const float* pdd        = (const float*)d_in[3];
  const int*   batch      = (const int*)  d_in[4];
  const float* atom_W1 = (const float*)d_in[5];
  const float* atom_b1 = (const float*)d_in[6];
  const float* atom_W2 = (const float*)d_in[7];
  const float* atom_b2 = (const float*)d_in[8];
  const float* edge_W  = (const float*)d_in[9];
  const float* edge_b  = (const float*)d_in[10];
  const float* pdd_W   = (const float*)d_in[11];
  const float* pdd_b   = (const float*)d_in[12];
  const float* conv_Wq = (const float*)d_in[13];
  const float* conv_bq = (const float*)d_in[14];
  const float* conv_Wk = (const float*)d_in[15];
  const float* conv_bk = (const float*)d_in[16];
  const float* conv_Wv = (const float*)d_in[17];
  const float* conv_bv = (const float*)d_in[18];
  const float* conv_We = (const float*)d_in[19];
  const float* conv_be = (const float*)d_in[20];
  const float* conv_Wku = (const float*)d_in[21];
  const float* conv_bku = (const float*)d_in[22];
  const float* conv_Wmu = (const float*)d_in[23];
  const float* conv_bmu = (const float*)d_in[24];
  const float* conv_Wm  = (const float*)d_in[25];
  const float* conv_bm  = (const float*)d_in[26];
  const float* ln_m_g = (const float*)d_in[27];
  const float* ln_m_b = (const float*)d_in[28];
  const float* ln_a_g = (const float*)d_in[29];
  const float* ln_a_b = (const float*)d_in[30];
  const float* bn_g   = (const float*)d_in[31];
  const float* bn_b   = (const float*)d_in[32];
  const float* pddc_W1 = (const float*)d_in[33];
  const float* pddc_b1 = (const float*)d_in[34];
  const float* pddc_W2 = (const float*)d_in[35];
  const float* pddc_b2 = (const float*)d_in[36];
  const float* pddc_W3 = (const float*)d_in[37];
  const float* pddc_b3 = (const float*)d_in[38];
  const float* pddc_bn_g = (const float*)d_in[39];
  const float* pddc_bn_b = (const float*)d_in[40];
  const float* fc_W  = (const float*)d_in[41];
  const float* fc_b  = (const float*)d_in[42];
  const float* out_W = (const float*)d_in[43];
  const float* out_b = (const float*)d_in[44];

  const int* src = edge_index;
  const int* dst = edge_index + Ne;

  // ---- workspace carve-up (~248 MB) ----
  char* ws = (char*)d_ws;
  size_t off = 0;
  auto alloc = [&](size_t nbytes) -> char* {
    char* ptr = ws + off;
    off += (nbytes + 255) & ~(size_t)255;
    return ptr;
  };
  bf16*  e_in = (bf16*) alloc((size_t)Ne * Cc * 2);   // dst-sorted
  bf16*  bufB = (bf16*) alloc((size_t)Ne * Cc * 2);   // pddc ub scratch
  bf16*  bufC = (bf16*) alloc((size_t)Ne * Cc * 2);   // embed scratch | pddc a2a,a2b
  float* x    = (float*)alloc((size_t)Nn * Cc * 4);
  float* p    = (float*)alloc((size_t)Nn * Cc * 4);
  float* agg  = (float*)alloc((size_t)Nn * Cc * 4);
  bf16*  x_bf  = (bf16*)alloc((size_t)Nn * Cc * 2);
  bf16*  q_bf  = (bf16*)alloc((size_t)Nn * Cc * 2);
  bf16*  kp1   = (bf16*)alloc((size_t)Nn * Cc * 2);
  bf16*  kp2   = (bf16*)alloc((size_t)Nn * Cc * 2);
  bf16*  vp1   = (bf16*)alloc((size_t)Nn * Cc * 2);
  bf16*  vp2   = (bf16*)alloc((size_t)Nn * Cc * 2);
  bf16*  WpN5  = (bf16*)alloc((size_t)3 * 5 * 65536 * 2);
  bf16*  WpEdge= (bf16*)alloc((size_t)3 * 2 * 65536 * 2);
  bf16*  WpM   = (bf16*)alloc((size_t)3 * 65536 * 2);
  bf16*  WpE   = (bf16*)alloc((size_t)65536 * 2);
  bf16*  WpP1  = (bf16*)alloc((size_t)2 * 2 * 65536 * 2);
  bf16*  WpP2  = (bf16*)alloc((size_t)2 * 65536 * 2);
  bf16*  WpP3  = (bf16*)alloc((size_t)2 * 65536 * 2);
  float* nodeb = (float*)alloc((size_t)3 * 1280 * 4);
  float* b_edge= (float*)alloc((size_t)3 * 512 * 4);
  int*   hist    = (int*)alloc((size_t)8192 * 4);
  int*   rowptr  = (int*)alloc((size_t)8193 * 4);
  int*   counter = (int*)alloc((size_t)8192 * 4);
  int*   pos     = (int*)alloc((size_t)Ne * 4);
  int*   dstS    = (int*)alloc((size_t)Ne * 4);
  int*   srcS    = (int*)alloc((size_t)Ne * 4);
  float* pooled = (float*)alloc((size_t)Bb * Cc * 4);
  float* counts = (float*)alloc((size_t)Bb * 4);
  float* cf     = (float*)alloc((size_t)Bb * Cc * 4);
  float* bnsum  = (float*)alloc(4 * Cc * 4);   // [0,512): layer BN; [512,1024): pddc BN

  // embedding-time aliases inside bufC
  float* hidden = (float*)(bufC + (size_t)1024 * 1024);
  // pddc-time aliases
  bf16* a2a = bufC;
  bf16* a2b = bufC + (size_t)Nn * Cc;
  bf16* ub  = bufB;

  // ---- segment structures ----
  zero_i_k<<<dim3(8), dim3(256), 0, stream>>>(hist, 8192);
  hist_k<<<dim3(Ne / 256), dim3(256), 0, stream>>>(dst, hist);
  scan_k<<<dim3(1), dim3(1024), 0, stream>>>(hist, rowptr, counter);
  perm_k<<<dim3(Ne / 256), dim3(256), 0, stream>>>(dst, counter, pos);
  sortidx_k<<<dim3(Ne / 256), dim3(256), 0, stream>>>(dst, src, pos, dstS, srcS);

  // ---- prep: batched folds + packs + bias folds ----
  fold_k<<<dim3(4, 2, 18), dim3(256), 0, stream>>>(
    conv_Wk, conv_Wv, conv_We, conv_Wku, conv_Wmu, WpN5, WpEdge);
  pack_qm_k<<<dim3(256, 6), dim3(256), 0, stream>>>(conv_Wq, conv_Wm, WpN5, WpM);
  fuse_bias_all_k<<<dim3(6), dim3(256), 0, stream>>>(
    conv_bku, conv_bmu, conv_be, conv_bk, conv_bv, conv_Wku, conv_Wmu, b_edge);
  nodeb_all_k<<<dim3(15), dim3(256), 0, stream>>>(conv_bq, nodeb);
  pack_b2_k<<<dim3(256, 1), dim3(256), 0, stream>>>(edge_W, 256, WpE);
  for (int j = 0; j < 2; j++){
    pack_b2_k<<<dim3(256, 2), dim3(256), 0, stream>>>(
      pddc_W1 + (size_t)j * 256 * 512, 512, WpP1 + (size_t)j * 2 * 65536);
    pack_b2_k<<<dim3(256, 1), dim3(256), 0, stream>>>(
      pddc_W2 + (size_t)j * 65536, 256, WpP2 + (size_t)j * 65536);
    pack_b2_k<<<dim3(256, 1), dim3(256), 0, stream>>>(
      pddc_W3 + (size_t)j * 65536, 256, WpP3 + (size_t)j * 65536);
  }

  // ---- embeddings ----
  launch_gemm(stream, node, 92, 92, Nn, Cc, atom_W1, atom_b1,
              nullptr, 0, hidden, 0, 1);
  launch_gemm(stream, hidden, 256, 256, Nn, Cc, atom_W2, atom_b2,
              nullptr, 0, x, 0, 0);
  f2bf_k<<<dim3(512), dim3(256), 0, stream>>>(x_bf, x, (long)Nn * Cc);
  launch_gemm(stream, pdd, 51, 51, Nn, Cc, pdd_W, pdd_b,
              nullptr, 0, p, 0, 0);
  // e_in = silu(rbf(d(edge_attr)) @ edge_W + edge_b), sorted out
  rbf_mg_k<<<dim3(Ne / 64), dim3(256), 0, stream>>>(edge_attr, WpE, edge_b, e_in, pos);

  for (int i = 0; i < 3; i++){
    // q, kp1, kp2, vp1, vp2 (5-panel)
    launch_mg(stream, Nn, 5, x_bf, WpN5 + (size_t)i * 5 * 65536, nodeb + i * 1280,
              q_bf, kp1, kp2, vp1, vp2, nullptr, nullptr, 0, nullptr);
    // zero agg + bnsum(1024) in one dispatch
    zero2_k<<<dim3(1024), dim3(256), 0, stream>>>(agg, (long)Nn * Cc, bnsum, 1024);
    conv_edge_k<<<dim3(Ne / 32), dim3(256), 0, stream>>>(
      e_in, WpEdge + (size_t)i * 2 * 65536, b_edge + i * 512,
      WpM + (size_t)i * 65536, conv_bm + i * 256,
      q_bf, kp1, kp2, vp1, vp2, dstS, srcS,
      ln_a_g + i * 256, ln_a_b + i * 256, agg);
    bn_stats_f<<<dim3(Nn / 128), dim3(256), 0, stream>>>(agg, rowptr,
              ln_m_g + i * 256, ln_m_b + i * 256, bnsum);

    if (i < 2){
      int j = i;
      // x = softplus(x + BN(y)); p += x; p-stats -> bnsum[512:]
      bn_apply_padd_k<<<dim3(Nn / 128), dim3(256), 0, stream>>>(
              x, x_bf, p, agg, rowptr,
              ln_m_g + i * 256, ln_m_b + i * 256, bnsum,
              bn_g + i * 256, bn_b + i * 256, bnsum + 512);
      bnaff_st_k<<<dim3(Nn), dim3(256), 0, stream>>>(p, bnsum + 512,
              pddc_bn_g + j * 256, pddc_bn_b + j * 256, x_bf);
      launch_mg(stream, Nn, 2, x_bf, WpP1 + (size_t)j * 2 * 65536, pddc_b1 + j * 512,
                a2a, a2b, nullptr, nullptr, nullptr, nullptr, nullptr, 0, nullptr);
      // u = (a2a@W2 + b2) * gelu(a2b)   (fused epilogue)
      launch_mg(stream, Nn, 1, a2a, WpP2 + (size_t)j * 65536, pddc_b2 + j * 256,
                ub, nullptr, nullptr, nullptr, nullptr, nullptr, nullptr, 0, nullptr,
                a2b);
      // x = u @ W3 + b3 + x  (fp32 in-place, bf16 shadow refresh)
      launch_mg(stream, Nn, 1, ub, WpP3 + (size_t)j * 65536, pddc_b3 + j * 256,
                nullptr, nullptr, nullptr, nullptr, nullptr, x, x_bf, 0, nullptr);
    } else {
      bn_apply_softplus_f<<<dim3(Nn), dim3(256), 0, stream>>>(x, x_bf, agg, rowptr,
              ln_m_g + i * 256, ln_m_b + i * 256, bnsum,
              bn_g + i * 256, bn_b + i * 256);
    }
  }

  // ---- pooling + head ----
  zero2_k<<<dim3(64), dim3(256), 0, stream>>>(pooled, (long)Bb * Cc, counts, Bb);
  pool_k<<<dim3(Nn), dim3(256), 0, stream>>>(x, batch, pooled, counts);
  pooldiv_k<<<dim3(Bb), dim3(256), 0, stream>>>(pooled, counts);
  launch_gemm(stream, pooled, 256, 256, Bb, Cc, fc_W, fc_b,
              pooled, Cc, cf, 0, 1);
  out_k<<<dim3(Bb), dim3(256), 0, stream>>>(cf, out_W, out_b, (float*)d_out);
}

// Round 17
// 1535.873 us; speedup vs baseline: 1.1212x; 1.1212x over previous
//
#include <hip/hip_runtime.h>
#include <hip/hip_bf16.h>

#define Nn 8192
#define Ne 131072
#define Cc 256
#define Bb 64

typedef __hip_bfloat16 bf16;
typedef __attribute__((ext_vector_type(8))) short bf16x8;
typedef __attribute__((ext_vector_type(4))) float f32x4;

__device__ __forceinline__ float b2f(unsigned short s){
  return __uint_as_float(((unsigned)s) << 16);
}
__device__ __forceinline__ unsigned short f2b(float v){
  bf16 h = __float2bfloat16(v);
  return *(unsigned short*)&h;
}

__device__ __forceinline__ void block_reduce_2(float& s1, float& s2, float* sm){
#pragma unroll
  for (int off = 32; off > 0; off >>= 1){
    s1 += __shfl_down(s1, off, 64);
    s2 += __shfl_down(s2, off, 64);
  }
  int lane = threadIdx.x & 63;
  int wid  = threadIdx.x >> 6;
  if (lane == 0){ sm[wid] = s1; sm[4 + wid] = s2; }
  __syncthreads();
  s1 = sm[0] + sm[1] + sm[2] + sm[3];
  s2 = sm[4] + sm[5] + sm[6] + sm[7];
}

// ================= mg_k: bf16 MFMA GEMM, K=256, contiguous A =================
// gelAux: if non-null, epilogue v = (acc+bias) * gelu_exact(aux[row,col]).
__global__ __launch_bounds__(256) void mg_k(
  const bf16* __restrict__ A,
  const bf16* __restrict__ Bpack, const float* __restrict__ bias,
  bf16* __restrict__ o0, bf16* __restrict__ o1, bf16* __restrict__ o2,
  bf16* __restrict__ o3, bf16* __restrict__ o4,
  float* __restrict__ fout, bf16* __restrict__ foutBf,
  int actMode, const int* __restrict__ outPerm,
  const bf16* __restrict__ gelAux)
{
  int lane = threadIdx.x & 63;
  int wave = threadIdx.x >> 6;
  int panel = blockIdx.x;
  long m0 = (long)blockIdx.y * 64;
  int row16 = lane & 15;
  int kg    = lane >> 4;

  const bf16* a0 = A + (m0 + row16) * 256 + kg * 8;
  const bf16* bp = Bpack + (size_t)panel * 65536;

  f32x4 acc[4][4];
#pragma unroll
  for (int i = 0; i < 4; i++)
#pragma unroll
    for (int j = 0; j < 4; j++) acc[i][j] = (f32x4){0.f, 0.f, 0.f, 0.f};

#pragma unroll
  for (int c8 = 0; c8 < 8; c8++){
    bf16x8 a[4], b[4];
#pragma unroll
    for (int im = 0; im < 4; im++)
      a[im] = *(const bf16x8*)(a0 + im * 4096 + c8 * 32);
#pragma unroll
    for (int in = 0; in < 4; in++)
      b[in] = *(const bf16x8*)(bp + ((size_t)((c8 * 16 + wave * 4 + in) * 64 + lane)) * 8);
#pragma unroll
    for (int im = 0; im < 4; im++)
#pragma unroll
      for (int in = 0; in < 4; in++)
        acc[im][in] = __builtin_amdgcn_mfma_f32_16x16x32_bf16(
                        a[im], b[in], acc[im][in], 0, 0, 0);
  }

  int colq = lane & 15;
  int quad = lane >> 4;

  if (fout){
#pragma unroll
    for (int im = 0; im < 4; im++)
#pragma unroll
      for (int in = 0; in < 4; in++){
        int col = wave * 64 + in * 16 + colq;
        float bv = bias ? bias[col] : 0.f;
#pragma unroll
        for (int r = 0; r < 4; r++){
          long row = m0 + im * 16 + quad * 4 + r;
          float v = acc[im][in][r] + bv + fout[row * 256 + col];
          fout[row * 256 + col] = v;
          if (foutBf) foutBf[row * 256 + col] = __float2bfloat16(v);
        }
      }
    return;
  }

  bf16* op = (panel == 0) ? o0 : (panel == 1) ? o1 : (panel == 2) ? o2
           : (panel == 3) ? o3 : o4;
#pragma unroll
  for (int im = 0; im < 4; im++){
    long orow[4];
#pragma unroll
    for (int r = 0; r < 4; r++){
      long row = m0 + im * 16 + quad * 4 + r;
      orow[r] = outPerm ? (long)outPerm[row] : row;
    }
#pragma unroll
    for (int in = 0; in < 4; in++){
      int col = wave * 64 + in * 16 + colq;
      float bv = bias ? bias[panel * 256 + col] : 0.f;
#pragma unroll
      for (int r = 0; r < 4; r++){
        long row = m0 + im * 16 + quad * 4 + r;
        float v = acc[im][in][r] + bv;
        if (actMode == 1) v = v / (1.f + __expf(-v));
        if (gelAux){
          float xg = b2f(((const unsigned short*)gelAux)[row * 256 + col]);
          v *= 0.5f * xg * (1.0f + erff(xg * 0.70710678118654752f));
        }
        op[orow[r] * 256 + col] = __float2bfloat16(v);
      }
    }
  }
}

// ================= rbf_mg_k: e_in = silu(rbf(d(ea)) @ W + b) ================
__global__ __launch_bounds__(256) void rbf_mg_k(
  const float* __restrict__ ea,
  const bf16* __restrict__ Bpack, const float* __restrict__ bias,
  bf16* __restrict__ out, const int* __restrict__ outPerm)
{
  int lane = threadIdx.x & 63;
  int wave = threadIdx.x >> 6;
  long m0 = (long)blockIdx.x * 64;
  int row16 = lane & 15;
  int kg    = lane >> 4;

  float dv[4];
#pragma unroll
  for (int im = 0; im < 4; im++){
    long r = m0 + row16 + im * 16;
    float a = ea[r * 3 + 0], b = ea[r * 3 + 1], c = ea[r * 3 + 2];
    dv[im] = -rsqrtf(a * a + b * b + c * c);
  }

  f32x4 acc[4][4];
#pragma unroll
  for (int i = 0; i < 4; i++)
#pragma unroll
    for (int j = 0; j < 4; j++) acc[i][j] = (f32x4){0.f, 0.f, 0.f, 0.f};

#pragma unroll
  for (int c8 = 0; c8 < 8; c8++){
    bf16x8 a[4], b[4];
#pragma unroll
    for (int im = 0; im < 4; im++){
#pragma unroll
      for (int j = 0; j < 8; j++){
        int k = c8 * 32 + kg * 8 + j;
        float cen = -6.0f + (float)k * (6.0f / 255.0f);
        float df  = dv[im] - cen;
        a[im][j] = (short)f2b(__expf(-42.5f * df * df));
      }
    }
#pragma unroll
    for (int in = 0; in < 4; in++)
      b[in] = *(const bf16x8*)(Bpack + ((size_t)((c8 * 16 + wave * 4 + in) * 64 + lane)) * 8);
#pragma unroll
    for (int im = 0; im < 4; im++)
#pragma unroll
      for (int in = 0; in < 4; in++)
        acc[im][in] = __builtin_amdgcn_mfma_f32_16x16x32_bf16(
                        a[im], b[in], acc[im][in], 0, 0, 0);
  }

  int colq = lane & 15;
  int quad = lane >> 4;
#pragma unroll
  for (int im = 0; im < 4; im++){
    long orow[4];
#pragma unroll
    for (int r = 0; r < 4; r++){
      long row = m0 + im * 16 + quad * 4 + r;
      orow[r] = outPerm ? (long)outPerm[row] : row;
    }
#pragma unroll
    for (int in = 0; in < 4; in++){
      int col = wave * 64 + in * 16 + colq;
      float bv = bias[col];
#pragma unroll
      for (int r = 0; r < 4; r++){
        float v = acc[im][in][r] + bv;
        v = v / (1.f + __expf(-v));     // silu
        out[orow[r] * 256 + col] = __float2bfloat16(v);
      }
    }
  }
}

// ================= conv_edge_k: fused edge pipeline + segment-sum ============
__global__ __launch_bounds__(256) void conv_edge_k(
  const bf16* __restrict__ e_in,
  const bf16* __restrict__ Bedge, const float* __restrict__ bedge,
  const bf16* __restrict__ Bm, const float* __restrict__ bm,
  const bf16* __restrict__ q,
  const bf16* __restrict__ kp1, const bf16* __restrict__ kp2,
  const bf16* __restrict__ vp1, const bf16* __restrict__ vp2,
  const int* __restrict__ dstS, const int* __restrict__ srcS,
  const float* __restrict__ lg, const float* __restrict__ lb,
  float* __restrict__ aggS)
{
  __shared__ bf16 eK[32 * 256];   // 16 KB
  __shared__ bf16 eM[32 * 256];   // 16 KB
  __shared__ int  sdst[32];
  int lane = threadIdx.x & 63;
  int wave = threadIdx.x >> 6;
  long m0 = (long)blockIdx.x * 32;
  int row16 = lane & 15;
  int kg    = lane >> 4;
  int colq  = row16;
  int quad  = kg;

  if (threadIdx.x < 32) sdst[threadIdx.x] = dstS[m0 + threadIdx.x];

  int drs[8], srs[8];
#pragma unroll
  for (int it = 0; it < 8; it++){
    drs[it] = dstS[m0 + it * 4 + wave];
    srs[it] = srcS[m0 + it * 4 + wave];
  }
  int c0g = lane * 4;
  ushort4 k1 = *(const ushort4*)((const unsigned short*)kp1 + (long)drs[0] * 256 + c0g);
  ushort4 k2 = *(const ushort4*)((const unsigned short*)kp2 + (long)srs[0] * 256 + c0g);
  ushort4 qv = *(const ushort4*)((const unsigned short*)q   + (long)drs[0] * 256 + c0g);
  ushort4 v1 = *(const ushort4*)((const unsigned short*)vp1 + (long)drs[0] * 256 + c0g);
  ushort4 v2 = *(const ushort4*)((const unsigned short*)vp2 + (long)srs[0] * 256 + c0g);

  const bf16* a0 = e_in + (m0 + row16) * 256 + kg * 8;

  for (int p = 0; p < 2; p++){
    const bf16* bp = Bedge + (size_t)p * 65536;
    f32x4 acc[2][4];
#pragma unroll
    for (int i = 0; i < 2; i++)
#pragma unroll
      for (int j = 0; j < 4; j++) acc[i][j] = (f32x4){0.f, 0.f, 0.f, 0.f};
#pragma unroll
    for (int c8 = 0; c8 < 8; c8++){
      bf16x8 a[2], b[4];
#pragma unroll
      for (int im = 0; im < 2; im++)
        a[im] = *(const bf16x8*)(a0 + im * 4096 + c8 * 32);
#pragma unroll
      for (int in = 0; in < 4; in++)
        b[in] = *(const bf16x8*)(bp + ((size_t)((c8 * 16 + wave * 4 + in) * 64 + lane)) * 8);
#pragma unroll
      for (int im = 0; im < 2; im++)
#pragma unroll
        for (int in = 0; in < 4; in++)
          acc[im][in] = __builtin_amdgcn_mfma_f32_16x16x32_bf16(
                          a[im], b[in], acc[im][in], 0, 0, 0);
    }
    bf16* E = p ? eM : eK;
    const float* bb = bedge + p * 256;
#pragma unroll
    for (int im = 0; im < 2; im++)
#pragma unroll
      for (int in = 0; in < 4; in++){
        int col = wave * 64 + in * 16 + colq;
        float bv = bb[col];
#pragma unroll
        for (int r = 0; r < 4; r++){
          int row = im * 16 + quad * 4 + r;
          int idx = row * 256 + ((((col >> 3) ^ (row & 7))) << 3) + (col & 7);
          E[idx] = __float2bfloat16(acc[im][in][r] + bv);
        }
      }
  }
  __syncthreads();

  // gate
  {
    int cb = lane >> 1;
    int e0 = (lane & 1) * 4;
    float4 gv = *(const float4*)(lg + c0g);
    float4 bv = *(const float4*)(lb + c0g);
#pragma unroll
    for (int it = 0; it < 8; it++){
      int row = it * 4 + wave;
      int li = row * 256 + ((cb ^ (row & 7)) << 3) + e0;
      ushort4 ek = *(const ushort4*)((const unsigned short*)eK + li);
      ushort4 em = *(const ushort4*)((const unsigned short*)eM + li);
      ushort4 nk1, nk2, nqv, nv1, nv2;
      if (it < 7){
        long dr2 = drs[it + 1], sr2 = srs[it + 1];
        nk1 = *(const ushort4*)((const unsigned short*)kp1 + dr2 * 256 + c0g);
        nk2 = *(const ushort4*)((const unsigned short*)kp2 + sr2 * 256 + c0g);
        nqv = *(const ushort4*)((const unsigned short*)q   + dr2 * 256 + c0g);
        nv1 = *(const ushort4*)((const unsigned short*)vp1 + dr2 * 256 + c0g);
        nv2 = *(const ushort4*)((const unsigned short*)vp2 + sr2 * 256 + c0g);
      }
      float a0g = (b2f(ek.x) + b2f(k1.x) + b2f(k2.x)) * b2f(qv.x) * 0.0625f;
      float a1g = (b2f(ek.y) + b2f(k1.y) + b2f(k2.y)) * b2f(qv.y) * 0.0625f;
      float a2g = (b2f(ek.z) + b2f(k1.z) + b2f(k2.z)) * b2f(qv.z) * 0.0625f;
      float a3g = (b2f(ek.w) + b2f(k1.w) + b2f(k2.w)) * b2f(qv.w) * 0.0625f;
      float s1 = a0g + a1g + a2g + a3g;
      float s2 = a0g*a0g + a1g*a1g + a2g*a2g + a3g*a3g;
#pragma unroll
      for (int off = 1; off < 64; off <<= 1){
        s1 += __shfl_xor(s1, off, 64);
        s2 += __shfl_xor(s2, off, 64);
      }
      float mn  = s1 * (1.0f / Cc);
      float var = s2 * (1.0f / Cc) - mn * mn;
      float rs  = rsqrtf(var + 1e-5f);
      float g0 = 1.f / (1.f + __expf(-((a0g - mn) * rs * gv.x + bv.x)));
      float g1 = 1.f / (1.f + __expf(-((a1g - mn) * rs * gv.y + bv.y)));
      float g2 = 1.f / (1.f + __expf(-((a2g - mn) * rs * gv.z + bv.z)));
      float g3 = 1.f / (1.f + __expf(-((a3g - mn) * rs * gv.w + bv.w)));
      ushort4 o;
      o.x = f2b((b2f(em.x) + b2f(v1.x) + b2f(v2.x)) * g0);
      o.y = f2b((b2f(em.y) + b2f(v1.y) + b2f(v2.y)) * g1);
      o.z = f2b((b2f(em.z) + b2f(v1.z) + b2f(v2.z)) * g2);
      o.w = f2b((b2f(em.w) + b2f(v1.w) + b2f(v2.w)) * g3);
      *(ushort4*)((unsigned short*)eK + li) = o;
      k1 = nk1; k2 = nk2; qv = nqv; v1 = nv1; v2 = nv2;
    }
  }
  __syncthreads();

  // msg @ Wm
  f32x4 acc[2][4];
#pragma unroll
  for (int i = 0; i < 2; i++)
#pragma unroll
    for (int j = 0; j < 4; j++) acc[i][j] = (f32x4){0.f, 0.f, 0.f, 0.f};
  int r7 = row16 & 7;
#pragma unroll
  for (int c8 = 0; c8 < 8; c8++){
    bf16x8 a[2], b[4];
#pragma unroll
    for (int im = 0; im < 2; im++)
      a[im] = *(const bf16x8*)&eK[(row16 + im * 16) * 256 + (((c8 * 4 + kg) ^ r7) << 3)];
#pragma unroll
    for (int in = 0; in < 4; in++)
      b[in] = *(const bf16x8*)(Bm + ((size_t)((c8 * 16 + wave * 4 + in) * 64 + lane)) * 8);
#pragma unroll
    for (int im = 0; im < 2; im++)
#pragma unroll
      for (int in = 0; in < 4; in++)
        acc[im][in] = __builtin_amdgcn_mfma_f32_16x16x32_bf16(
                        a[im], b[in], acc[im][in], 0, 0, 0);
  }

  // row LN -> eM
  float s1a[2][4], s2a[2][4];
#pragma unroll
  for (int im = 0; im < 2; im++)
#pragma unroll
    for (int r = 0; r < 4; r++){
      float t1 = 0.f, t2 = 0.f;
#pragma unroll
      for (int in = 0; in < 4; in++){
        int col = wave * 64 + in * 16 + colq;
        float v = acc[im][in][r] + bm[col];
        t1 += v; t2 += v * v;
      }
#pragma unroll
      for (int off = 1; off < 16; off <<= 1){
        t1 += __shfl_xor(t1, off, 64);
        t2 += __shfl_xor(t2, off, 64);
      }
      s1a[im][r] = t1; s2a[im][r] = t2;
    }
  __syncthreads();
  float* red = (float*)eK;
  if (colq < 8){
    int imw = colq >> 2, rw = colq & 3;
    int rr = imw * 16 + quad * 4 + rw;
    red[(wave * 32 + rr) * 2 + 0] = s1a[imw][rw];
    red[(wave * 32 + rr) * 2 + 1] = s2a[imw][rw];
  }
  __syncthreads();
#pragma unroll
  for (int im = 0; im < 2; im++)
#pragma unroll
    for (int r = 0; r < 4; r++){
      int row = im * 16 + quad * 4 + r;
      float ts1 = red[row * 2]           + red[(32 + row) * 2]
                + red[(64 + row) * 2]    + red[(96 + row) * 2];
      float ts2 = red[row * 2 + 1]       + red[(32 + row) * 2 + 1]
                + red[(64 + row) * 2 + 1] + red[(96 + row) * 2 + 1];
      float mn  = ts1 * (1.0f / Cc);
      float var = ts2 * (1.0f / Cc) - mn * mn;
      float rs  = rsqrtf(var + 1e-5f);
#pragma unroll
      for (int in = 0; in < 4; in++){
        int col = wave * 64 + in * 16 + colq;
        float v = acc[im][in][r] + bm[col];
        ((unsigned short*)eM)[row * 256 + col] = f2b((v - mn) * rs);
      }
    }
  __syncthreads();

  // segment-sum over dst runs
  {
    int t = threadIdx.x;
    float sum = 0.f;
    int cur = sdst[0];
    for (int r = 0; r < 32; r++){
      int d = sdst[r];
      if (d != cur){
        atomicAdd(&aggS[(long)cur * 256 + t], sum);
        sum = 0.f; cur = d;
      }
      sum += b2f(((const unsigned short*)eM)[r * 256 + t]);
    }
    atomicAdd(&aggS[(long)cur * 256 + t], sum);
  }
}

// ---------------- pack fp32 W[k][panel*256+n] -> bf16 fragment layout --------
__global__ __launch_bounds__(256) void pack_b2_k(
  const float* __restrict__ W, int ldW, bf16* __restrict__ out)
{
  int panel = blockIdx.y;
  long p = (long)blockIdx.x * 256 + threadIdx.x;
  int j    = p & 7;
  int lane = (p >> 3) & 63;
  int nt   = (p >> 9) & 15;
  int kc   = p >> 13;
  int k = kc * 32 + (lane >> 4) * 8 + j;
  int n = nt * 16 + (lane & 15);
  out[(size_t)panel * 65536 + p] =
    __float2bfloat16(W[(long)k * ldW + panel * 256 + n]);
}

// batched pack
__global__ __launch_bounds__(256) void pack_qm_k(
  const float* __restrict__ Wq, const float* __restrict__ Wm,
  bf16* __restrict__ N5, bf16* __restrict__ WpM)
{
  int z = blockIdx.y;
  const float* W; bf16* out;
  if (z < 3){ W = Wq + (size_t)z * 65536; out = N5 + (size_t)z * 327680; }
  else      { W = Wm + (size_t)(z-3) * 65536; out = WpM + (size_t)(z-3) * 65536; }
  long p = (long)blockIdx.x * 256 + threadIdx.x;
  int j    = p & 7;
  int lane = (p >> 3) & 63;
  int nt   = (p >> 9) & 15;
  int kc   = p >> 13;
  int k = kc * 32 + (lane >> 4) * 8 + j;
  int n = nt * 16 + (lane & 15);
  out[p] = __float2bfloat16(W[(long)k * 256 + n]);
}

// ================= fold_k: batched 256x256x256 fp32 GEMM -> packed bf16 ======
__global__ __launch_bounds__(256) void fold_k(
  const float* __restrict__ Wk, const float* __restrict__ Wv,
  const float* __restrict__ We,
  const float* __restrict__ Wku, const float* __restrict__ Wmu,
  bf16* __restrict__ N5, bf16* __restrict__ EG)
{
  int z = blockIdx.z, i = z / 6, j = z % 6;
  const float* A; const float* B; bf16* C;
  if (j < 2){
    A = Wk + (size_t)i * 65536; B = Wku + (size_t)i * 196608 + j * 65536;
    C = N5 + (size_t)i * 327680 + (size_t)(1 + j) * 65536;
  } else if (j < 4){
    A = Wv + (size_t)i * 65536; B = Wmu + (size_t)i * 196608 + (j - 2) * 65536;
    C = N5 + (size_t)i * 327680 + (size_t)(3 + (j - 2)) * 65536;
  } else {
    A = We + (size_t)i * 65536;
    B = (j == 4 ? Wku : Wmu) + (size_t)i * 196608 + 131072;
    C = EG + (size_t)i * 131072 + (size_t)(j - 4) * 65536;
  }

  __shared__ __align__(16) float As[16][64];
  __shared__ __align__(16) float Bs[16][128];
  int t = threadIdx.x;
  int m0 = blockIdx.x * 64;
  int n0 = blockIdx.y * 128;

  float acc[4][8];
#pragma unroll
  for (int a = 0; a < 4; a++)
#pragma unroll
    for (int b = 0; b < 8; b++) acc[a][b] = 0.f;
  int tm = t >> 4, tn = t & 15, mA = t & 63, kgA = t >> 6;

  for (int k0 = 0; k0 < 256; k0 += 16){
#pragma unroll
    for (int it = 0; it < 4; it++){
      int kl = kgA + it * 4;
      As[kl][mA] = A[(long)(m0 + mA) * 256 + k0 + kl];
    }
#pragma unroll
    for (int it = 0; it < 8; it++){
      int idx = t + it * 256;
      int kl = idx >> 7, n = idx & 127;
      Bs[kl][n] = B[(long)(k0 + kl) * 256 + n0 + n];
    }
    __syncthreads();
#pragma unroll
    for (int kk = 0; kk < 16; kk++){
      float4 a  = *(const float4*)&As[kk][tm * 4];
      float4 b0 = *(const float4*)&Bs[kk][tn * 4];
      float4 b1 = *(const float4*)&Bs[kk][64 + tn * 4];
      float av[4] = {a.x, a.y, a.z, a.w};
      float bv[8] = {b0.x, b0.y, b0.z, b0.w, b1.x, b1.y, b1.z, b1.w};
#pragma unroll
      for (int ii = 0; ii < 4; ii++)
#pragma unroll
        for (int jj = 0; jj < 8; jj++)
          acc[ii][jj] = __builtin_fmaf(av[ii], bv[jj], acc[ii][jj]);
    }
    __syncthreads();
  }
#pragma unroll
  for (int ii = 0; ii < 4; ii++){
    int m = m0 + tm * 4 + ii;
#pragma unroll
    for (int h = 0; h < 2; h++){
#pragma unroll
      for (int jj = 0; jj < 4; jj++){
        int n = n0 + h * 64 + tn * 4 + jj;
        int kc = m >> 5, nt = n >> 4;
        int ln_ = ((m >> 3) & 3) * 16 + (n & 15);
        long idx = ((long)(kc * 16 + nt) * 64 + ln_) * 8 + (m & 7);
        C[idx] = __float2bfloat16(acc[ii][h * 4 + jj]);
      }
    }
  }
}

// ================= generic fp32 tiled GEMM (embeddings / head) ==============
__global__ __launch_bounds__(256) void gemm_k(
  const void* __restrict__ A0, int K0, int ld0,
  long M, int Nout,
  const float* __restrict__ W, const float* __restrict__ bias,
  const float* __restrict__ res, int ldRes,
  void* __restrict__ Cout, int outDt, int actMode)
{
  __shared__ __align__(16) float As[16][64];
  __shared__ __align__(16) float Bs[16][128];

  int t = threadIdx.x;
  long m0 = (long)blockIdx.x * 64;
  int  n0 = blockIdx.y * 128;

  float acc[4][8];
#pragma unroll
  for (int i = 0; i < 4; i++)
#pragma unroll
    for (int j = 0; j < 8; j++) acc[i][j] = 0.f;

  int tm = t >> 4, tn = t & 15, mA = t & 63, kgA = t >> 6;
  long rowA = m0 + mA;
  bool rv = rowA < M;

  for (int k0 = 0; k0 < K0; k0 += 16){
#pragma unroll
    for (int it = 0; it < 4; it++){
      int kl = kgA + it * 4;
      int k  = k0 + kl;
      float v = 0.f;
      if (rv && k < K0) v = ((const float*)A0)[rowA * (long)ld0 + k];
      As[kl][mA] = v;
    }
#pragma unroll
    for (int it = 0; it < 8; it++){
      int idx = t + it * 256;
      int kl = idx >> 7, n = idx & 127;
      int k  = k0 + kl;
      Bs[kl][n] = (k < K0) ? W[(long)k * Nout + n0 + n] : 0.f;
    }
    __syncthreads();
#pragma unroll
    for (int kk = 0; kk < 16; kk++){
      float4 a  = *(const float4*)&As[kk][tm * 4];
      float4 b0 = *(const float4*)&Bs[kk][tn * 4];
      float4 b1 = *(const float4*)&Bs[kk][64 + tn * 4];
      float av[4] = {a.x, a.y, a.z, a.w};
      float bv[8] = {b0.x, b0.y, b0.z, b0.w, b1.x, b1.y, b1.z, b1.w};
#pragma unroll
      for (int i = 0; i < 4; i++)
#pragma unroll
        for (int j = 0; j < 8; j++)
          acc[i][j] = __builtin_fmaf(av[i], bv[j], acc[i][j]);
    }
    __syncthreads();
  }

#pragma unroll
  for (int i = 0; i < 4; i++){
    long m = m0 + tm * 4 + i;
    if (m >= M) continue;
#pragma unroll
    for (int h = 0; h < 2; h++){
      int nb = n0 + h * 64 + tn * 4;
      float po[4];
#pragma unroll
      for (int j = 0; j < 4; j++){
        float v = acc[i][h * 4 + j];
        if (bias) v += bias[nb + j];
        if (actMode == 1) v = v / (1.0f + __expf(-v));
        if (res) v += res[m * (long)ldRes + nb + j];
        po[j] = v;
      }
      if (outDt){
        __align__(8) unsigned short tb[4];
#pragma unroll
        for (int j = 0; j < 4; j++) tb[j] = f2b(po[j]);
        *(short4*)((bf16*)Cout + m * (long)Nout + nb) = *(short4*)tb;
      } else {
        float4 ov = {po[0], po[1], po[2], po[3]};
        *(float4*)((float*)Cout + m * (long)Nout + nb) = ov;
      }
    }
  }
}

// ---------------- utility ----------------
__global__ __launch_bounds__(256) void zero2_k(float* __restrict__ a, long na,
                                               float* __restrict__ b2, long nb){
  long i = (long)blockIdx.x * 256 + threadIdx.x;
  long stride = (long)gridDim.x * 256;
  for (long j = i; j < na; j += stride) a[j] = 0.f;
  for (long j = i; j < nb; j += stride) b2[j] = 0.f;
}
__global__ __launch_bounds__(256) void zero_i_k(int* __restrict__ p, long n){
  long i = (long)blockIdx.x * 256 + threadIdx.x;
  long stride = (long)gridDim.x * 256;
  for (; i < n; i += stride) p[i] = 0;
}
__global__ __launch_bounds__(256) void f2bf_k(bf16* __restrict__ d,
                                              const float* __restrict__ s, long n){
  long i = (long)blockIdx.x * 256 + threadIdx.x;
  long stride = (long)gridDim.x * 256;
  for (; i < n; i += stride) d[i] = __float2bfloat16(s[i]);
}

// batched bias fold: z = i*2+kind
__global__ __launch_bounds__(256) void fuse_bias_all_k(
  const float* __restrict__ bku, const float* __restrict__ bmu,
  const float* __restrict__ be,
  const float* __restrict__ bk, const float* __restrict__ bv,
  const float* __restrict__ Wku, const float* __restrict__ Wmu,
  float* __restrict__ b_edge)
{
  int z = blockIdx.x, i = z >> 1, kind = z & 1;
  const float* W  = (kind ? Wmu : Wku) + (size_t)i * 196608;
  const float* b0 = (kind ? bmu : bku) + i * 256;
  const float* vb = (kind ? bv : bk) + i * 256;
  const float* eb = be + i * 256;
  int n = threadIdx.x;
  float s = b0[n];
  for (int k = 0; k < Cc; k++){
    s += eb[k] * W[(512 + k) * 256 + n];
    s += vb[k] * (W[k * 256 + n] + W[(256 + k) * 256 + n]);
  }
  b_edge[i * 512 + kind * 256 + n] = s;
}

// node5 bias for all layers
__global__ __launch_bounds__(256) void nodeb_all_k(const float* __restrict__ bq,
                                                   float* __restrict__ out){
  int z = blockIdx.x, i = z / 5, p = z % 5;
  out[i * 1280 + p * 256 + threadIdx.x] = (p == 0) ? bq[i * 256 + threadIdx.x] : 0.f;
}

// ---------------- segment sort ----------------
__global__ __launch_bounds__(256) void hist_k(const int* __restrict__ dst,
                                              int* __restrict__ hist)
{
  int e = blockIdx.x * 256 + threadIdx.x;
  if (e < Ne) atomicAdd(&hist[dst[e]], 1);
}

__global__ __launch_bounds__(1024) void scan_k(
  const int* __restrict__ hist, int* __restrict__ rowptr, int* __restrict__ counter)
{
  __shared__ int part[1024];
  int t = threadIdx.x;
  int base = t * 8;
  int local[8];
  int s = 0;
#pragma unroll
  for (int i = 0; i < 8; i++){ local[i] = s; s += hist[base + i]; }
  part[t] = s;
  __syncthreads();
  for (int off = 1; off < 1024; off <<= 1){
    int v = (t >= off) ? part[t - off] : 0;
    __syncthreads();
    part[t] += v;
    __syncthreads();
  }
  int pre = (t == 0) ? 0 : part[t - 1];
#pragma unroll
  for (int i = 0; i < 8; i++){
    int rp = pre + local[i];
    rowptr[base + i] = rp;
    counter[base + i] = rp;
  }
  if (t == 1023) rowptr[8192] = part[1023];
}

__global__ __launch_bounds__(256) void perm_k(const int* __restrict__ dst,
                                              int* __restrict__ counter,
                                              int* __restrict__ pos)
{
  int e = blockIdx.x * 256 + threadIdx.x;
  if (e < Ne) pos[e] = atomicAdd(&counter[dst[e]], 1);
}

__global__ __launch_bounds__(256) void sortidx_k(
  const int* __restrict__ dst, const int* __restrict__ srcI,
  const int* __restrict__ pos, int* __restrict__ dstS, int* __restrict__ srcS)
{
  int e = blockIdx.x * 256 + threadIdx.x;
  if (e < Ne){
    int p = pos[e];
    dstS[p] = dst[e];
    srcS[p] = srcI[e];
  }
}

// ---------------- BatchNorm over y[n][c] = lg[c]*S[n][c] + cnt[n]*lb[c] ------
__global__ __launch_bounds__(256) void bn_stats_f(
  const float* __restrict__ S, const int* __restrict__ rowptr,
  const float* __restrict__ lg, const float* __restrict__ lb,
  float* __restrict__ sums)
{
  int c  = threadIdx.x;
  int r0 = blockIdx.x * 128;
  float gc = lg[c], bc = lb[c];
  float s1 = 0.f, s2 = 0.f;
  for (int r = r0; r < r0 + 128; r++){
    float cnt = (float)(rowptr[r + 1] - rowptr[r]);
    float y = gc * S[(long)r * Cc + c] + cnt * bc;
    s1 += y; s2 += y * y;
  }
  atomicAdd(&sums[c],      s1);
  atomicAdd(&sums[Cc + c], s2);
}

// layer 2 (no pddc): x = softplus(x + BN(y))
__global__ __launch_bounds__(256) void bn_apply_softplus_f(
  float* __restrict__ x, bf16* __restrict__ xbf,
  const float* __restrict__ S, const int* __restrict__ rowptr,
  const float* __restrict__ lg, const float* __restrict__ lb,
  const float* __restrict__ sums,
  const float* __restrict__ g, const float* __restrict__ b)
{
  long r = blockIdx.x;
  int c = threadIdx.x;
  float cnt = (float)(rowptr[r + 1] - rowptr[r]);
  float y = lg[c] * S[r * Cc + c] + cnt * lb[c];
  float m    = sums[c] * (1.0f / Nn);
  float var  = sums[Cc + c] * (1.0f / Nn) - m * m;
  float rstd = rsqrtf(var + 1e-5f);
  float bn = (y - m) * rstd * g[c] + b[c];
  float v  = x[r * Cc + c] + bn;
  float sp = (v > 0.f) ? v + log1pf(__expf(-v)) : log1pf(__expf(v));
  x[r * Cc + c] = sp;
  xbf[r * Cc + c] = __float2bfloat16(sp);
}

// layers 0-1: fused apply + p += sp + p-stats -> sums2 (16 rows/block, 512 blocks)
__global__ __launch_bounds__(256) void bn_apply_padd_k(
  float* __restrict__ x, bf16* __restrict__ xbf, float* __restrict__ p,
  const float* __restrict__ S, const int* __restrict__ rowptr,
  const float* __restrict__ lg, const float* __restrict__ lb,
  const float* __restrict__ sums,
  const float* __restrict__ g, const float* __restrict__ b,
  float* __restrict__ sums2)
{
  int c  = threadIdx.x;
  int r0 = blockIdx.x * 16;
  float gc = lg[c], bc = lb[c];
  float m    = sums[c] * (1.0f / Nn);
  float var  = sums[Cc + c] * (1.0f / Nn) - m * m;
  float rstd = rsqrtf(var + 1e-5f);
  float bg = g[c], bb2 = b[c];
  float s1 = 0.f, s2 = 0.f;
  for (int r = r0; r < r0 + 16; r++){
    long idx = (long)r * Cc + c;
    float cnt = (float)(rowptr[r + 1] - rowptr[r]);
    float y = gc * S[idx] + cnt * bc;
    float bn = (y - m) * rstd * bg + bb2;
    float v  = x[idx] + bn;
    float sp = (v > 0.f) ? v + log1pf(__expf(-v)) : log1pf(__expf(v));
    x[idx] = sp;
    xbf[idx] = __float2bfloat16(sp);
    float pv = p[idx] + sp;
    p[idx] = pv;
    s1 += pv; s2 += pv * pv;
  }
  atomicAdd(&sums2[c],      s1);
  atomicAdd(&sums2[Cc + c], s2);
}

// adj_bf = bf16(p*S + T), S/T computed inline from sums2
__global__ __launch_bounds__(256) void bnaff_st_k(
  const float* __restrict__ p, const float* __restrict__ sums,
  const float* __restrict__ g, const float* __restrict__ b,
  bf16* __restrict__ out)
{
  long r = blockIdx.x;
  int c = threadIdx.x;
  float m    = sums[c] * (1.0f / Nn);
  float var  = sums[Cc + c] * (1.0f / Nn) - m * m;
  float rstd = rsqrtf(var + 1e-5f);
  float S = g[c] * rstd;
  float T = b[c] - m * rstd * g[c];
  out[r * 256 + c] = __float2bfloat16(p[r * 256 + c] * S + T);
}

__global__ __launch_bounds__(256) void pool_k(
  const float* __restrict__ x, const int* __restrict__ batch,
  float* __restrict__ pooled, float* __restrict__ counts)
{
  long r = blockIdx.x;
  int c = threadIdx.x;
  long b = batch[r];
  atomicAdd(&pooled[b * Cc + c], x[r * Cc + c]);
  if (c == 0) atomicAdd(&counts[b], 1.0f);
}

__global__ __launch_bounds__(256) void pooldiv_k(
  float* __restrict__ pooled, const float* __restrict__ counts)
{
  int b = blockIdx.x;
  int c = threadIdx.x;
  float cnt = counts[b];
  if (cnt < 1.f) cnt = 1.f;
  pooled[b * Cc + c] /= cnt;
}

__global__ __launch_bounds__(256) void out_k(
  const float* __restrict__ cf, const float* __restrict__ ow,
  const float* __restrict__ ob, float* __restrict__ out)
{
  __shared__ float sm[8];
  int b = blockIdx.x;
  int c = threadIdx.x;
  float v = cf[(long)b * Cc + c] * ow[c];
  float dummy = 0.f;
  block_reduce_2(v, dummy, sm);
  if (c == 0) out[b] = v + ob[0];
}

// ---------------- host helpers ----------------
static inline void launch_gemm(hipStream_t st,
  const void* A0, int K0, int ld0,
  long M, int Nout, const float* W, const float* bias,
  const float* res, int ldRes, void* Cout, int outDt, int act)
{
  dim3 grid((unsigned)((M + 63) / 64), (unsigned)(Nout / 128));
  gemm_k<<<grid, dim3(256), 0, st>>>(
    A0, K0, ld0, M, Nout, W, bias, res, ldRes, Cout, outDt, act);
}

static inline void launch_mg(hipStream_t st, long M, int panels,
  const bf16* A, const bf16* Bpack, const float* bias,
  bf16* o0, bf16* o1, bf16* o2, bf16* o3, bf16* o4,
  float* fout, bf16* foutBf, int act, const int* outPerm,
  const bf16* gelAux = nullptr)
{
  dim3 grid((unsigned)panels, (unsigned)(M / 64));
  mg_k<<<grid, dim3(256), 0, st>>>(A, Bpack, bias, o0, o1, o2, o3, o4,
                                   fout, foutBf, act, outPerm, gelAux);
}

extern "C" void kernel_launch(void* const* d_in, const int* in_sizes, int n_in,
                              void* d_out, int out_size, void* d_ws, size_t ws_size,
                              hipStream_t stream)
{
  (void)in_sizes; (void)n_in; (void)out_size; (void)ws_size;

  const float* node       = (const float*)d_in[0];
  const int*   edge_index = (const int*)  d_in[1];
  const float* edge_attr  = (const float*)d_in[2];
  const float* pdd        = (const float*)d_in[3];
  const int*   batch      = (const int*)  d_in[4];
  const float* atom_W1 = (const float*)d_in[5];
  const float* atom_b1 = (const float*)d_in[6];
  const float* atom_W2 = (const float*)d_in[7];
  const float* atom_b2 = (const float*)d_in[8];
  const float* edge_W  = (const float*)d_in[9];
  const float* edge_b  = (const float*)d_in[10];
  const float* pdd_W   = (const float*)d_in[11];
  const float* pdd_b   = (const float*)d_in[12];
  const float* conv_Wq = (const float*)d_in[13];
  const float* conv_bq = (const float*)d_in[14];
  const float* conv_Wk = (const float*)d_in[15];
  const float* conv_bk = (const float*)d_in[16];
  const float* conv_Wv = (const float*)d_in[17];
  const float* conv_bv = (const float*)d_in[18];
  const float* conv_We = (const float*)d_in[19];
  const float* conv_be = (const float*)d_in[20];
  const float* conv_Wku = (const float*)d_in[21];
  const float* conv_bku = (const float*)d_in[22];
  const float* conv_Wmu = (const float*)d_in[23];
  const float* conv_bmu = (const float*)d_in[24];
  const float* conv_Wm  = (const float*)d_in[25];
  const float* conv_bm  = (const float*)d_in[26];
  const float* ln_m_g = (const float*)d_in[27];
  const float* ln_m_b = (const float*)d_in[28];
  const float* ln_a_g = (const float*)d_in[29];
  const float* ln_a_b = (const float*)d_in[30];
  const float* bn_g   = (const float*)d_in[31];
  const float* bn_b   = (const float*)d_in[32];
  const float* pddc_W1 = (const float*)d_in[33];
  const float* pddc_b1 = (const float*)d_in[34];
  const float* pddc_W2 = (const float*)d_in[35];
  const float* pddc_b2 = (const float*)d_in[36];
  const float* pddc_W3 = (const float*)d_in[37];
  const float* pddc_b3 = (const float*)d_in[38];
  const float* pddc_bn_g = (const float*)d_in[39];
  const float* pddc_bn_b = (const float*)d_in[40];
  const float* fc_W  = (const float*)d_in[41];
  const float* fc_b  = (const float*)d_in[42];
  const float* out_W = (const float*)d_in[43];
  const float* out_b = (const float*)d_in[44];

  const int* src = edge_index;
  const int* dst = edge_index + Ne;

  // ---- workspace carve-up (~248 MB) ----
  char* ws = (char*)d_ws;
  size_t off = 0;
  auto alloc = [&](size_t nbytes) -> char* {
    char* ptr = ws + off;
    off += (nbytes + 255) & ~(size_t)255;
    return ptr;
  };
  bf16*  e_in = (bf16*) alloc((size_t)Ne * Cc * 2);   // dst-sorted
  bf16*  bufB = (bf16*) alloc((size_t)Ne * Cc * 2);   // pddc ub scratch
  bf16*  bufC = (bf16*) alloc((size_t)Ne * Cc * 2);   // embed scratch | pddc a2a,a2b
  float* x    = (float*)alloc((size_t)Nn * Cc * 4);
  float* p    = (float*)alloc((size_t)Nn * Cc * 4);
  float* agg  = (float*)alloc((size_t)Nn * Cc * 4);
  bf16*  x_bf  = (bf16*)alloc((size_t)Nn * Cc * 2);
  bf16*  q_bf  = (bf16*)alloc((size_t)Nn * Cc * 2);
  bf16*  kp1   = (bf16*)alloc((size_t)Nn * Cc * 2);
  bf16*  kp2   = (bf16*)alloc((size_t)Nn * Cc * 2);
  bf16*  vp1   = (bf16*)alloc((size_t)Nn * Cc * 2);
  bf16*  vp2   = (bf16*)alloc((size_t)Nn * Cc * 2);
  bf16*  WpN5  = (bf16*)alloc((size_t)3 * 5 * 65536 * 2);
  bf16*  WpEdge= (bf16*)alloc((size_t)3 * 2 * 65536 * 2);
  bf16*  WpM   = (bf16*)alloc((size_t)3 * 65536 * 2);
  bf16*  WpE   = (bf16*)alloc((size_t)65536 * 2);
  bf16*  WpP1  = (bf16*)alloc((size_t)2 * 2 * 65536 * 2);
  bf16*  WpP2  = (bf16*)alloc((size_t)2 * 65536 * 2);
  bf16*  WpP3  = (bf16*)alloc((size_t)2 * 65536 * 2);
  float* nodeb = (float*)alloc((size_t)3 * 1280 * 4);
  float* b_edge= (float*)alloc((size_t)3 * 512 * 4);
  int*   hist    = (int*)alloc((size_t)8192 * 4);
  int*   rowptr  = (int*)alloc((size_t)8193 * 4);
  int*   counter = (int*)alloc((size_t)8192 * 4);
  int*   pos     = (int*)alloc((size_t)Ne * 4);
  int*   dstS    = (int*)alloc((size_t)Ne * 4);
  int*   srcS    = (int*)alloc((size_t)Ne * 4);
  float* pooled = (float*)alloc((size_t)Bb * Cc * 4);
  float* counts = (float*)alloc((size_t)Bb * 4);
  float* cf     = (float*)alloc((size_t)Bb * Cc * 4);
  float* bnsum  = (float*)alloc(4 * Cc * 4);   // [0,512): layer BN; [512,1024): pddc BN

  // embedding-time aliases inside bufC
  float* hidden = (float*)(bufC + (size_t)1024 * 1024);
  // pddc-time aliases
  bf16* a2a = bufC;
  bf16* a2b = bufC + (size_t)Nn * Cc;
  bf16* ub  = bufB;

  // ---- segment structures ----
  zero_i_k<<<dim3(8), dim3(256), 0, stream>>>(hist, 8192);
  hist_k<<<dim3(Ne / 256), dim3(256), 0, stream>>>(dst, hist);
  scan_k<<<dim3(1), dim3(1024), 0, stream>>>(hist, rowptr, counter);
  perm_k<<<dim3(Ne / 256), dim3(256), 0, stream>>>(dst, counter, pos);
  sortidx_k<<<dim3(Ne / 256), dim3(256), 0, stream>>>(dst, src, pos, dstS, srcS);

  // ---- prep: batched folds + packs + bias folds ----
  fold_k<<<dim3(4, 2, 18), dim3(256), 0, stream>>>(
    conv_Wk, conv_Wv, conv_We, conv_Wku, conv_Wmu, WpN5, WpEdge);
  pack_qm_k<<<dim3(256, 6), dim3(256), 0, stream>>>(conv_Wq, conv_Wm, WpN5, WpM);
  fuse_bias_all_k<<<dim3(6), dim3(256), 0, stream>>>(
    conv_bku, conv_bmu, conv_be, conv_bk, conv_bv, conv_Wku, conv_Wmu, b_edge);
  nodeb_all_k<<<dim3(15), dim3(256), 0, stream>>>(conv_bq, nodeb);
  pack_b2_k<<<dim3(256, 1), dim3(256), 0, stream>>>(edge_W, 256, WpE);
  for (int j = 0; j < 2; j++){
    pack_b2_k<<<dim3(256, 2), dim3(256), 0, stream>>>(
      pddc_W1 + (size_t)j * 256 * 512, 512, WpP1 + (size_t)j * 2 * 65536);
    pack_b2_k<<<dim3(256, 1), dim3(256), 0, stream>>>(
      pddc_W2 + (size_t)j * 65536, 256, WpP2 + (size_t)j * 65536);
    pack_b2_k<<<dim3(256, 1), dim3(256), 0, stream>>>(
      pddc_W3 + (size_t)j * 65536, 256, WpP3 + (size_t)j * 65536);
  }

  // ---- embeddings ----
  launch_gemm(stream, node, 92, 92, Nn, Cc, atom_W1, atom_b1,
              nullptr, 0, hidden, 0, 1);
  launch_gemm(stream, hidden, 256, 256, Nn, Cc, atom_W2, atom_b2,
              nullptr, 0, x, 0, 0);
  f2bf_k<<<dim3(512), dim3(256), 0, stream>>>(x_bf, x, (long)Nn * Cc);
  launch_gemm(stream, pdd, 51, 51, Nn, Cc, pdd_W, pdd_b,
              nullptr, 0, p, 0, 0);
  // e_in = silu(rbf(d(edge_attr)) @ edge_W + edge_b), sorted out
  rbf_mg_k<<<dim3(Ne / 64), dim3(256), 0, stream>>>(edge_attr, WpE, edge_b, e_in, pos);

  for (int i = 0; i < 3; i++){
    // q, kp1, kp2, vp1, vp2 (5-panel)
    launch_mg(stream, Nn, 5, x_bf, WpN5 + (size_t)i * 5 * 65536, nodeb + i * 1280,
              q_bf, kp1, kp2, vp1, vp2, nullptr, nullptr, 0, nullptr);
    // zero agg + bnsum(1024) in one dispatch
    zero2_k<<<dim3(1024), dim3(256), 0, stream>>>(agg, (long)Nn * Cc, bnsum, 1024);
    conv_edge_k<<<dim3(Ne / 32), dim3(256), 0, stream>>>(
      e_in, WpEdge + (size_t)i * 2 * 65536, b_edge + i * 512,
      WpM + (size_t)i * 65536, conv_bm + i * 256,
      q_bf, kp1, kp2, vp1, vp2, dstS, srcS,
      ln_a_g + i * 256, ln_a_b + i * 256, agg);
    bn_stats_f<<<dim3(Nn / 128), dim3(256), 0, stream>>>(agg, rowptr,
              ln_m_g + i * 256, ln_m_b + i * 256, bnsum);

    if (i < 2){
      int j = i;
      // x = softplus(x + BN(y)); p += x; p-stats -> bnsum[512:]  (512 blocks)
      bn_apply_padd_k<<<dim3(Nn / 16), dim3(256), 0, stream>>>(
              x, x_bf, p, agg, rowptr,
              ln_m_g + i * 256, ln_m_b + i * 256, bnsum,
              bn_g + i * 256, bn_b + i * 256, bnsum + 512);
      bnaff_st_k<<<dim3(Nn), dim3(256), 0, stream>>>(p, bnsum + 512,
              pddc_bn_g + j * 256, pddc_bn_b + j * 256, x_bf);
      launch_mg(stream, Nn, 2, x_bf, WpP1 + (size_t)j * 2 * 65536, pddc_b1 + j * 512,
                a2a, a2b, nullptr, nullptr, nullptr, nullptr, nullptr, 0, nullptr);
      // u = (a2a@W2 + b2) * gelu(a2b)   (fused epilogue)
      launch_mg(stream, Nn, 1, a2a, WpP2 + (size_t)j * 65536, pddc_b2 + j * 256,
                ub, nullptr, nullptr, nullptr, nullptr, nullptr, nullptr, 0, nullptr,
                a2b);
      // x = u @ W3 + b3 + x  (fp32 in-place, bf16 shadow refresh)
      launch_mg(stream, Nn, 1, ub, WpP3 + (size_t)j * 65536, pddc_b3 + j * 256,
                nullptr, nullptr, nullptr, nullptr, nullptr, x, x_bf, 0, nullptr);
    } else {
      bn_apply_softplus_f<<<dim3(Nn), dim3(256), 0, stream>>>(x, x_bf, agg, rowptr,
              ln_m_g + i * 256, ln_m_b + i * 256, bnsum,
              bn_g + i * 256, bn_b + i * 256);
    }
  }

  // ---- pooling + head ----
  zero2_k<<<dim3(64), dim3(256), 0, stream>>>(pooled, (long)Bb * Cc, counts, Bb);
  pool_k<<<dim3(Nn), dim3(256), 0, stream>>>(x, batch, pooled, counts);
  pooldiv_k<<<dim3(Bb), dim3(256), 0, stream>>>(pooled, counts);
  launch_gemm(stream, pooled, 256, 256, Bb, Cc, fc_W, fc_b,
              pooled, Cc, cf, 0, 1);
  out_k<<<dim3(Bb), dim3(256), 0, stream>>>(cf, out_W, out_b, (float*)d_out);
}

// Round 18
// 1524.349 us; speedup vs baseline: 1.1296x; 1.0076x over previous
//
#include <hip/hip_runtime.h>
#include <hip/hip_bf16.h>

#define Nn 8192
#define Ne 131072
#define Cc 256
#define Bb 64

typedef __hip_bfloat16 bf16;
typedef __attribute__((ext_vector_type(8))) short bf16x8;
typedef __attribute__((ext_vector_type(4))) float f32x4;

__device__ __forceinline__ float b2f(unsigned short s){
  return __uint_as_float(((unsigned)s) << 16);
}
__device__ __forceinline__ unsigned short f2b(float v){
  bf16 h = __float2bfloat16(v);
  return *(unsigned short*)&h;
}

__device__ __forceinline__ void block_reduce_2(float& s1, float& s2, float* sm){
#pragma unroll
  for (int off = 32; off > 0; off >>= 1){
    s1 += __shfl_down(s1, off, 64);
    s2 += __shfl_down(s2, off, 64);
  }
  int lane = threadIdx.x & 63;
  int wid  = threadIdx.x >> 6;
  if (lane == 0){ sm[wid] = s1; sm[4 + wid] = s2; }
  __syncthreads();
  s1 = sm[0] + sm[1] + sm[2] + sm[3];
  s2 = sm[4] + sm[5] + sm[6] + sm[7];
}

// ================= mg_k: bf16 MFMA GEMM, K=256, contiguous A =================
// gelAux: if non-null, epilogue v = (acc+bias) * gelu_exact(aux[row,col]).
__global__ __launch_bounds__(256) void mg_k(
  const bf16* __restrict__ A,
  const bf16* __restrict__ Bpack, const float* __restrict__ bias,
  bf16* __restrict__ o0, bf16* __restrict__ o1, bf16* __restrict__ o2,
  bf16* __restrict__ o3, bf16* __restrict__ o4,
  float* __restrict__ fout, bf16* __restrict__ foutBf,
  int actMode, const int* __restrict__ outPerm,
  const bf16* __restrict__ gelAux)
{
  int lane = threadIdx.x & 63;
  int wave = threadIdx.x >> 6;
  int panel = blockIdx.x;
  long m0 = (long)blockIdx.y * 64;
  int row16 = lane & 15;
  int kg    = lane >> 4;

  const bf16* a0 = A + (m0 + row16) * 256 + kg * 8;
  const bf16* bp = Bpack + (size_t)panel * 65536;

  f32x4 acc[4][4];
#pragma unroll
  for (int i = 0; i < 4; i++)
#pragma unroll
    for (int j = 0; j < 4; j++) acc[i][j] = (f32x4){0.f, 0.f, 0.f, 0.f};

#pragma unroll
  for (int c8 = 0; c8 < 8; c8++){
    bf16x8 a[4], b[4];
#pragma unroll
    for (int im = 0; im < 4; im++)
      a[im] = *(const bf16x8*)(a0 + im * 4096 + c8 * 32);
#pragma unroll
    for (int in = 0; in < 4; in++)
      b[in] = *(const bf16x8*)(bp + ((size_t)((c8 * 16 + wave * 4 + in) * 64 + lane)) * 8);
#pragma unroll
    for (int im = 0; im < 4; im++)
#pragma unroll
      for (int in = 0; in < 4; in++)
        acc[im][in] = __builtin_amdgcn_mfma_f32_16x16x32_bf16(
                        a[im], b[in], acc[im][in], 0, 0, 0);
  }

  int colq = lane & 15;
  int quad = lane >> 4;

  if (fout){
#pragma unroll
    for (int im = 0; im < 4; im++)
#pragma unroll
      for (int in = 0; in < 4; in++){
        int col = wave * 64 + in * 16 + colq;
        float bv = bias ? bias[col] : 0.f;
#pragma unroll
        for (int r = 0; r < 4; r++){
          long row = m0 + im * 16 + quad * 4 + r;
          float v = acc[im][in][r] + bv + fout[row * 256 + col];
          fout[row * 256 + col] = v;
          if (foutBf) foutBf[row * 256 + col] = __float2bfloat16(v);
        }
      }
    return;
  }

  bf16* op = (panel == 0) ? o0 : (panel == 1) ? o1 : (panel == 2) ? o2
           : (panel == 3) ? o3 : o4;
#pragma unroll
  for (int im = 0; im < 4; im++){
    long orow[4];
#pragma unroll
    for (int r = 0; r < 4; r++){
      long row = m0 + im * 16 + quad * 4 + r;
      orow[r] = outPerm ? (long)outPerm[row] : row;
    }
#pragma unroll
    for (int in = 0; in < 4; in++){
      int col = wave * 64 + in * 16 + colq;
      float bv = bias ? bias[panel * 256 + col] : 0.f;
#pragma unroll
      for (int r = 0; r < 4; r++){
        long row = m0 + im * 16 + quad * 4 + r;
        float v = acc[im][in][r] + bv;
        if (actMode == 1) v = v / (1.f + __expf(-v));
        if (gelAux){
          float xg = b2f(((const unsigned short*)gelAux)[row * 256 + col]);
          v *= 0.5f * xg * (1.0f + erff(xg * 0.70710678118654752f));
        }
        op[orow[r] * 256 + col] = __float2bfloat16(v);
      }
    }
  }
}

// ================= rbf_mg_k: e_in = silu(rbf(d(ea)) @ W + b) ================
__global__ __launch_bounds__(256) void rbf_mg_k(
  const float* __restrict__ ea,
  const bf16* __restrict__ Bpack, const float* __restrict__ bias,
  bf16* __restrict__ out, const int* __restrict__ outPerm)
{
  int lane = threadIdx.x & 63;
  int wave = threadIdx.x >> 6;
  long m0 = (long)blockIdx.x * 64;
  int row16 = lane & 15;
  int kg    = lane >> 4;

  float dv[4];
#pragma unroll
  for (int im = 0; im < 4; im++){
    long r = m0 + row16 + im * 16;
    float a = ea[r * 3 + 0], b = ea[r * 3 + 1], c = ea[r * 3 + 2];
    dv[im] = -rsqrtf(a * a + b * b + c * c);
  }

  f32x4 acc[4][4];
#pragma unroll
  for (int i = 0; i < 4; i++)
#pragma unroll
    for (int j = 0; j < 4; j++) acc[i][j] = (f32x4){0.f, 0.f, 0.f, 0.f};

#pragma unroll
  for (int c8 = 0; c8 < 8; c8++){
    bf16x8 a[4], b[4];
#pragma unroll
    for (int im = 0; im < 4; im++){
#pragma unroll
      for (int j = 0; j < 8; j++){
        int k = c8 * 32 + kg * 8 + j;
        float cen = -6.0f + (float)k * (6.0f / 255.0f);
        float df  = dv[im] - cen;
        a[im][j] = (short)f2b(__expf(-42.5f * df * df));
      }
    }
#pragma unroll
    for (int in = 0; in < 4; in++)
      b[in] = *(const bf16x8*)(Bpack + ((size_t)((c8 * 16 + wave * 4 + in) * 64 + lane)) * 8);
#pragma unroll
    for (int im = 0; im < 4; im++)
#pragma unroll
      for (int in = 0; in < 4; in++)
        acc[im][in] = __builtin_amdgcn_mfma_f32_16x16x32_bf16(
                        a[im], b[in], acc[im][in], 0, 0, 0);
  }

  int colq = lane & 15;
  int quad = lane >> 4;
#pragma unroll
  for (int im = 0; im < 4; im++){
    long orow[4];
#pragma unroll
    for (int r = 0; r < 4; r++){
      long row = m0 + im * 16 + quad * 4 + r;
      orow[r] = outPerm ? (long)outPerm[row] : row;
    }
#pragma unroll
    for (int in = 0; in < 4; in++){
      int col = wave * 64 + in * 16 + colq;
      float bv = bias[col];
#pragma unroll
      for (int r = 0; r < 4; r++){
        float v = acc[im][in][r] + bv;
        v = v / (1.f + __expf(-v));     // silu
        out[orow[r] * 256 + col] = __float2bfloat16(v);
      }
    }
  }
}

// ================= conv_edge_k: fused edge pipeline + segment-sum ============
// XCD-aware swizzle: consecutive blocks on one XCD cover a contiguous span of
// the dst-sorted edge stream (gather tables become per-XCD L2-resident).
__global__ __launch_bounds__(256) void conv_edge_k(
  const bf16* __restrict__ e_in,
  const bf16* __restrict__ Bedge, const float* __restrict__ bedge,
  const bf16* __restrict__ Bm, const float* __restrict__ bm,
  const bf16* __restrict__ q,
  const bf16* __restrict__ kp1, const bf16* __restrict__ kp2,
  const bf16* __restrict__ vp1, const bf16* __restrict__ vp2,
  const int* __restrict__ dstS, const int* __restrict__ srcS,
  const float* __restrict__ lg, const float* __restrict__ lb,
  float* __restrict__ aggS)
{
  __shared__ bf16 eK[32 * 256];   // 16 KB
  __shared__ bf16 eM[32 * 256];   // 16 KB
  __shared__ int  sdst[32];
  int lane = threadIdx.x & 63;
  int wave = threadIdx.x >> 6;
  // XCD swizzle: dispatcher assigns blockIdx round-robin over 8 XCDs; map
  // blockIdx so each XCD sees a contiguous 1/8 span of the edge stream.
  int nb8 = (int)(gridDim.x >> 3);
  long bid = (long)(blockIdx.x & 7) * nb8 + (blockIdx.x >> 3);
  long m0 = bid * 32;
  int row16 = lane & 15;
  int kg    = lane >> 4;
  int colq  = row16;
  int quad  = kg;

  if (threadIdx.x < 32) sdst[threadIdx.x] = dstS[m0 + threadIdx.x];

  int drs[8], srs[8];
#pragma unroll
  for (int it = 0; it < 8; it++){
    drs[it] = dstS[m0 + it * 4 + wave];
    srs[it] = srcS[m0 + it * 4 + wave];
  }
  int c0g = lane * 4;
  ushort4 k1 = *(const ushort4*)((const unsigned short*)kp1 + (long)drs[0] * 256 + c0g);
  ushort4 k2 = *(const ushort4*)((const unsigned short*)kp2 + (long)srs[0] * 256 + c0g);
  ushort4 qv = *(const ushort4*)((const unsigned short*)q   + (long)drs[0] * 256 + c0g);
  ushort4 v1 = *(const ushort4*)((const unsigned short*)vp1 + (long)drs[0] * 256 + c0g);
  ushort4 v2 = *(const ushort4*)((const unsigned short*)vp2 + (long)srs[0] * 256 + c0g);

  const bf16* a0 = e_in + (m0 + row16) * 256 + kg * 8;

  for (int p = 0; p < 2; p++){
    const bf16* bp = Bedge + (size_t)p * 65536;
    f32x4 acc[2][4];
#pragma unroll
    for (int i = 0; i < 2; i++)
#pragma unroll
      for (int j = 0; j < 4; j++) acc[i][j] = (f32x4){0.f, 0.f, 0.f, 0.f};
#pragma unroll
    for (int c8 = 0; c8 < 8; c8++){
      bf16x8 a[2], b[4];
#pragma unroll
      for (int im = 0; im < 2; im++)
        a[im] = *(const bf16x8*)(a0 + im * 4096 + c8 * 32);
#pragma unroll
      for (int in = 0; in < 4; in++)
        b[in] = *(const bf16x8*)(bp + ((size_t)((c8 * 16 + wave * 4 + in) * 64 + lane)) * 8);
#pragma unroll
      for (int im = 0; im < 2; im++)
#pragma unroll
        for (int in = 0; in < 4; in++)
          acc[im][in] = __builtin_amdgcn_mfma_f32_16x16x32_bf16(
                          a[im], b[in], acc[im][in], 0, 0, 0);
    }
    bf16* E = p ? eM : eK;
    const float* bb = bedge + p * 256;
#pragma unroll
    for (int im = 0; im < 2; im++)
#pragma unroll
      for (int in = 0; in < 4; in++){
        int col = wave * 64 + in * 16 + colq;
        float bv = bb[col];
#pragma unroll
        for (int r = 0; r < 4; r++){
          int row = im * 16 + quad * 4 + r;
          int idx = row * 256 + ((((col >> 3) ^ (row & 7))) << 3) + (col & 7);
          E[idx] = __float2bfloat16(acc[im][in][r] + bv);
        }
      }
  }
  __syncthreads();

  // gate
  {
    int cb = lane >> 1;
    int e0 = (lane & 1) * 4;
    float4 gv = *(const float4*)(lg + c0g);
    float4 bv = *(const float4*)(lb + c0g);
#pragma unroll
    for (int it = 0; it < 8; it++){
      int row = it * 4 + wave;
      int li = row * 256 + ((cb ^ (row & 7)) << 3) + e0;
      ushort4 ek = *(const ushort4*)((const unsigned short*)eK + li);
      ushort4 em = *(const ushort4*)((const unsigned short*)eM + li);
      ushort4 nk1, nk2, nqv, nv1, nv2;
      if (it < 7){
        long dr2 = drs[it + 1], sr2 = srs[it + 1];
        nk1 = *(const ushort4*)((const unsigned short*)kp1 + dr2 * 256 + c0g);
        nk2 = *(const ushort4*)((const unsigned short*)kp2 + sr2 * 256 + c0g);
        nqv = *(const ushort4*)((const unsigned short*)q   + dr2 * 256 + c0g);
        nv1 = *(const ushort4*)((const unsigned short*)vp1 + dr2 * 256 + c0g);
        nv2 = *(const ushort4*)((const unsigned short*)vp2 + sr2 * 256 + c0g);
      }
      float a0g = (b2f(ek.x) + b2f(k1.x) + b2f(k2.x)) * b2f(qv.x) * 0.0625f;
      float a1g = (b2f(ek.y) + b2f(k1.y) + b2f(k2.y)) * b2f(qv.y) * 0.0625f;
      float a2g = (b2f(ek.z) + b2f(k1.z) + b2f(k2.z)) * b2f(qv.z) * 0.0625f;
      float a3g = (b2f(ek.w) + b2f(k1.w) + b2f(k2.w)) * b2f(qv.w) * 0.0625f;
      float s1 = a0g + a1g + a2g + a3g;
      float s2 = a0g*a0g + a1g*a1g + a2g*a2g + a3g*a3g;
#pragma unroll
      for (int off = 1; off < 64; off <<= 1){
        s1 += __shfl_xor(s1, off, 64);
        s2 += __shfl_xor(s2, off, 64);
      }
      float mn  = s1 * (1.0f / Cc);
      float var = s2 * (1.0f / Cc) - mn * mn;
      float rs  = rsqrtf(var + 1e-5f);
      float g0 = 1.f / (1.f + __expf(-((a0g - mn) * rs * gv.x + bv.x)));
      float g1 = 1.f / (1.f + __expf(-((a1g - mn) * rs * gv.y + bv.y)));
      float g2 = 1.f / (1.f + __expf(-((a2g - mn) * rs * gv.z + bv.z)));
      float g3 = 1.f / (1.f + __expf(-((a3g - mn) * rs * gv.w + bv.w)));
      ushort4 o;
      o.x = f2b((b2f(em.x) + b2f(v1.x) + b2f(v2.x)) * g0);
      o.y = f2b((b2f(em.y) + b2f(v1.y) + b2f(v2.y)) * g1);
      o.z = f2b((b2f(em.z) + b2f(v1.z) + b2f(v2.z)) * g2);
      o.w = f2b((b2f(em.w) + b2f(v1.w) + b2f(v2.w)) * g3);
      *(ushort4*)((unsigned short*)eK + li) = o;
      k1 = nk1; k2 = nk2; qv = nqv; v1 = nv1; v2 = nv2;
    }
  }
  __syncthreads();

  // msg @ Wm
  f32x4 acc[2][4];
#pragma unroll
  for (int i = 0; i < 2; i++)
#pragma unroll
    for (int j = 0; j < 4; j++) acc[i][j] = (f32x4){0.f, 0.f, 0.f, 0.f};
  int r7 = row16 & 7;
#pragma unroll
  for (int c8 = 0; c8 < 8; c8++){
    bf16x8 a[2], b[4];
#pragma unroll
    for (int im = 0; im < 2; im++)
      a[im] = *(const bf16x8*)&eK[(row16 + im * 16) * 256 + (((c8 * 4 + kg) ^ r7) << 3)];
#pragma unroll
    for (int in = 0; in < 4; in++)
      b[in] = *(const bf16x8*)(Bm + ((size_t)((c8 * 16 + wave * 4 + in) * 64 + lane)) * 8);
#pragma unroll
    for (int im = 0; im < 2; im++)
#pragma unroll
      for (int in = 0; in < 4; in++)
        acc[im][in] = __builtin_amdgcn_mfma_f32_16x16x32_bf16(
                        a[im], b[in], acc[im][in], 0, 0, 0);
  }

  // row LN -> eM
  float s1a[2][4], s2a[2][4];
#pragma unroll
  for (int im = 0; im < 2; im++)
#pragma unroll
    for (int r = 0; r < 4; r++){
      float t1 = 0.f, t2 = 0.f;
#pragma unroll
      for (int in = 0; in < 4; in++){
        int col = wave * 64 + in * 16 + colq;
        float v = acc[im][in][r] + bm[col];
        t1 += v; t2 += v * v;
      }
#pragma unroll
      for (int off = 1; off < 16; off <<= 1){
        t1 += __shfl_xor(t1, off, 64);
        t2 += __shfl_xor(t2, off, 64);
      }
      s1a[im][r] = t1; s2a[im][r] = t2;
    }
  __syncthreads();
  float* red = (float*)eK;
  if (colq < 8){
    int imw = colq >> 2, rw = colq & 3;
    int rr = imw * 16 + quad * 4 + rw;
    red[(wave * 32 + rr) * 2 + 0] = s1a[imw][rw];
    red[(wave * 32 + rr) * 2 + 1] = s2a[imw][rw];
  }
  __syncthreads();
#pragma unroll
  for (int im = 0; im < 2; im++)
#pragma unroll
    for (int r = 0; r < 4; r++){
      int row = im * 16 + quad * 4 + r;
      float ts1 = red[row * 2]           + red[(32 + row) * 2]
                + red[(64 + row) * 2]    + red[(96 + row) * 2];
      float ts2 = red[row * 2 + 1]       + red[(32 + row) * 2 + 1]
                + red[(64 + row) * 2 + 1] + red[(96 + row) * 2 + 1];
      float mn  = ts1 * (1.0f / Cc);
      float var = ts2 * (1.0f / Cc) - mn * mn;
      float rs  = rsqrtf(var + 1e-5f);
#pragma unroll
      for (int in = 0; in < 4; in++){
        int col = wave * 64 + in * 16 + colq;
        float v = acc[im][in][r] + bm[col];
        ((unsigned short*)eM)[row * 256 + col] = f2b((v - mn) * rs);
      }
    }
  __syncthreads();

  // segment-sum over dst runs
  {
    int t = threadIdx.x;
    float sum = 0.f;
    int cur = sdst[0];
    for (int r = 0; r < 32; r++){
      int d = sdst[r];
      if (d != cur){
        atomicAdd(&aggS[(long)cur * 256 + t], sum);
        sum = 0.f; cur = d;
      }
      sum += b2f(((const unsigned short*)eM)[r * 256 + t]);
    }
    atomicAdd(&aggS[(long)cur * 256 + t], sum);
  }
}

// ---------------- pack fp32 W[k][panel*256+n] -> bf16 fragment layout --------
__global__ __launch_bounds__(256) void pack_b2_k(
  const float* __restrict__ W, int ldW, bf16* __restrict__ out)
{
  int panel = blockIdx.y;
  long p = (long)blockIdx.x * 256 + threadIdx.x;
  int j    = p & 7;
  int lane = (p >> 3) & 63;
  int nt   = (p >> 9) & 15;
  int kc   = p >> 13;
  int k = kc * 32 + (lane >> 4) * 8 + j;
  int n = nt * 16 + (lane & 15);
  out[(size_t)panel * 65536 + p] =
    __float2bfloat16(W[(long)k * ldW + panel * 256 + n]);
}

// batched pack
__global__ __launch_bounds__(256) void pack_qm_k(
  const float* __restrict__ Wq, const float* __restrict__ Wm,
  bf16* __restrict__ N5, bf16* __restrict__ WpM)
{
  int z = blockIdx.y;
  const float* W; bf16* out;
  if (z < 3){ W = Wq + (size_t)z * 65536; out = N5 + (size_t)z * 327680; }
  else      { W = Wm + (size_t)(z-3) * 65536; out = WpM + (size_t)(z-3) * 65536; }
  long p = (long)blockIdx.x * 256 + threadIdx.x;
  int j    = p & 7;
  int lane = (p >> 3) & 63;
  int nt   = (p >> 9) & 15;
  int kc   = p >> 13;
  int k = kc * 32 + (lane >> 4) * 8 + j;
  int n = nt * 16 + (lane & 15);
  out[p] = __float2bfloat16(W[(long)k * 256 + n]);
}

// ================= fold_k: batched 256x256x256 fp32 GEMM -> packed bf16 ======
__global__ __launch_bounds__(256) void fold_k(
  const float* __restrict__ Wk, const float* __restrict__ Wv,
  const float* __restrict__ We,
  const float* __restrict__ Wku, const float* __restrict__ Wmu,
  bf16* __restrict__ N5, bf16* __restrict__ EG)
{
  int z = blockIdx.z, i = z / 6, j = z % 6;
  const float* A; const float* B; bf16* C;
  if (j < 2){
    A = Wk + (size_t)i * 65536; B = Wku + (size_t)i * 196608 + j * 65536;
    C = N5 + (size_t)i * 327680 + (size_t)(1 + j) * 65536;
  } else if (j < 4){
    A = Wv + (size_t)i * 65536; B = Wmu + (size_t)i * 196608 + (j - 2) * 65536;
    C = N5 + (size_t)i * 327680 + (size_t)(3 + (j - 2)) * 65536;
  } else {
    A = We + (size_t)i * 65536;
    B = (j == 4 ? Wku : Wmu) + (size_t)i * 196608 + 131072;
    C = EG + (size_t)i * 131072 + (size_t)(j - 4) * 65536;
  }

  __shared__ __align__(16) float As[16][64];
  __shared__ __align__(16) float Bs[16][128];
  int t = threadIdx.x;
  int m0 = blockIdx.x * 64;
  int n0 = blockIdx.y * 128;

  float acc[4][8];
#pragma unroll
  for (int a = 0; a < 4; a++)
#pragma unroll
    for (int b = 0; b < 8; b++) acc[a][b] = 0.f;
  int tm = t >> 4, tn = t & 15, mA = t & 63, kgA = t >> 6;

  for (int k0 = 0; k0 < 256; k0 += 16){
#pragma unroll
    for (int it = 0; it < 4; it++){
      int kl = kgA + it * 4;
      As[kl][mA] = A[(long)(m0 + mA) * 256 + k0 + kl];
    }
#pragma unroll
    for (int it = 0; it < 8; it++){
      int idx = t + it * 256;
      int kl = idx >> 7, n = idx & 127;
      Bs[kl][n] = B[(long)(k0 + kl) * 256 + n0 + n];
    }
    __syncthreads();
#pragma unroll
    for (int kk = 0; kk < 16; kk++){
      float4 a  = *(const float4*)&As[kk][tm * 4];
      float4 b0 = *(const float4*)&Bs[kk][tn * 4];
      float4 b1 = *(const float4*)&Bs[kk][64 + tn * 4];
      float av[4] = {a.x, a.y, a.z, a.w};
      float bv[8] = {b0.x, b0.y, b0.z, b0.w, b1.x, b1.y, b1.z, b1.w};
#pragma unroll
      for (int ii = 0; ii < 4; ii++)
#pragma unroll
        for (int jj = 0; jj < 8; jj++)
          acc[ii][jj] = __builtin_fmaf(av[ii], bv[jj], acc[ii][jj]);
    }
    __syncthreads();
  }
#pragma unroll
  for (int ii = 0; ii < 4; ii++){
    int m = m0 + tm * 4 + ii;
#pragma unroll
    for (int h = 0; h < 2; h++){
#pragma unroll
      for (int jj = 0; jj < 4; jj++){
        int n = n0 + h * 64 + tn * 4 + jj;
        int kc = m >> 5, nt = n >> 4;
        int ln_ = ((m >> 3) & 3) * 16 + (n & 15);
        long idx = ((long)(kc * 16 + nt) * 64 + ln_) * 8 + (m & 7);
        C[idx] = __float2bfloat16(acc[ii][h * 4 + jj]);
      }
    }
  }
}

// ================= generic fp32 tiled GEMM (embeddings / head) ==============
__global__ __launch_bounds__(256) void gemm_k(
  const void* __restrict__ A0, int K0, int ld0,
  long M, int Nout,
  const float* __restrict__ W, const float* __restrict__ bias,
  const float* __restrict__ res, int ldRes,
  void* __restrict__ Cout, int outDt, int actMode)
{
  __shared__ __align__(16) float As[16][64];
  __shared__ __align__(16) float Bs[16][128];

  int t = threadIdx.x;
  long m0 = (long)blockIdx.x * 64;
  int  n0 = blockIdx.y * 128;

  float acc[4][8];
#pragma unroll
  for (int i = 0; i < 4; i++)
#pragma unroll
    for (int j = 0; j < 8; j++) acc[i][j] = 0.f;

  int tm = t >> 4, tn = t & 15, mA = t & 63, kgA = t >> 6;
  long rowA = m0 + mA;
  bool rv = rowA < M;

  for (int k0 = 0; k0 < K0; k0 += 16){
#pragma unroll
    for (int it = 0; it < 4; it++){
      int kl = kgA + it * 4;
      int k  = k0 + kl;
      float v = 0.f;
      if (rv && k < K0) v = ((const float*)A0)[rowA * (long)ld0 + k];
      As[kl][mA] = v;
    }
#pragma unroll
    for (int it = 0; it < 8; it++){
      int idx = t + it * 256;
      int kl = idx >> 7, n = idx & 127;
      int k  = k0 + kl;
      Bs[kl][n] = (k < K0) ? W[(long)k * Nout + n0 + n] : 0.f;
    }
    __syncthreads();
#pragma unroll
    for (int kk = 0; kk < 16; kk++){
      float4 a  = *(const float4*)&As[kk][tm * 4];
      float4 b0 = *(const float4*)&Bs[kk][tn * 4];
      float4 b1 = *(const float4*)&Bs[kk][64 + tn * 4];
      float av[4] = {a.x, a.y, a.z, a.w};
      float bv[8] = {b0.x, b0.y, b0.z, b0.w, b1.x, b1.y, b1.z, b1.w};
#pragma unroll
      for (int i = 0; i < 4; i++)
#pragma unroll
        for (int j = 0; j < 8; j++)
          acc[i][j] = __builtin_fmaf(av[i], bv[j], acc[i][j]);
    }
    __syncthreads();
  }

#pragma unroll
  for (int i = 0; i < 4; i++){
    long m = m0 + tm * 4 + i;
    if (m >= M) continue;
#pragma unroll
    for (int h = 0; h < 2; h++){
      int nb = n0 + h * 64 + tn * 4;
      float po[4];
#pragma unroll
      for (int j = 0; j < 4; j++){
        float v = acc[i][h * 4 + j];
        if (bias) v += bias[nb + j];
        if (actMode == 1) v = v / (1.0f + __expf(-v));
        if (res) v += res[m * (long)ldRes + nb + j];
        po[j] = v;
      }
      if (outDt){
        __align__(8) unsigned short tb[4];
#pragma unroll
        for (int j = 0; j < 4; j++) tb[j] = f2b(po[j]);
        *(short4*)((bf16*)Cout + m * (long)Nout + nb) = *(short4*)tb;
      } else {
        float4 ov = {po[0], po[1], po[2], po[3]};
        *(float4*)((float*)Cout + m * (long)Nout + nb) = ov;
      }
    }
  }
}

// ---------------- utility ----------------
__global__ __launch_bounds__(256) void zero2_k(float* __restrict__ a, long na,
                                               float* __restrict__ b2, long nb){
  long i = (long)blockIdx.x * 256 + threadIdx.x;
  long stride = (long)gridDim.x * 256;
  for (long j = i; j < na; j += stride) a[j] = 0.f;
  for (long j = i; j < nb; j += stride) b2[j] = 0.f;
}
__global__ __launch_bounds__(256) void zero_i_k(int* __restrict__ p, long n){
  long i = (long)blockIdx.x * 256 + threadIdx.x;
  long stride = (long)gridDim.x * 256;
  for (; i < n; i += stride) p[i] = 0;
}
__global__ __launch_bounds__(256) void f2bf_k(bf16* __restrict__ d,
                                              const float* __restrict__ s, long n){
  long i = (long)blockIdx.x * 256 + threadIdx.x;
  long stride = (long)gridDim.x * 256;
  for (; i < n; i += stride) d[i] = __float2bfloat16(s[i]);
}

// batched bias fold: z = i*2+kind
__global__ __launch_bounds__(256) void fuse_bias_all_k(
  const float* __restrict__ bku, const float* __restrict__ bmu,
  const float* __restrict__ be,
  const float* __restrict__ bk, const float* __restrict__ bv,
  const float* __restrict__ Wku, const float* __restrict__ Wmu,
  float* __restrict__ b_edge)
{
  int z = blockIdx.x, i = z >> 1, kind = z & 1;
  const float* W  = (kind ? Wmu : Wku) + (size_t)i * 196608;
  const float* b0 = (kind ? bmu : bku) + i * 256;
  const float* vb = (kind ? bv : bk) + i * 256;
  const float* eb = be + i * 256;
  int n = threadIdx.x;
  float s = b0[n];
  for (int k = 0; k < Cc; k++){
    s += eb[k] * W[(512 + k) * 256 + n];
    s += vb[k] * (W[k * 256 + n] + W[(256 + k) * 256 + n]);
  }
  b_edge[i * 512 + kind * 256 + n] = s;
}

// node5 bias for all layers
__global__ __launch_bounds__(256) void nodeb_all_k(const float* __restrict__ bq,
                                                   float* __restrict__ out){
  int z = blockIdx.x, i = z / 5, p = z % 5;
  out[i * 1280 + p * 256 + threadIdx.x] = (p == 0) ? bq[i * 256 + threadIdx.x] : 0.f;
}

// ---------------- segment sort ----------------
__global__ __launch_bounds__(256) void hist_k(const int* __restrict__ dst,
                                              int* __restrict__ hist)
{
  int e = blockIdx.x * 256 + threadIdx.x;
  if (e < Ne) atomicAdd(&hist[dst[e]], 1);
}

__global__ __launch_bounds__(1024) void scan_k(
  const int* __restrict__ hist, int* __restrict__ rowptr, int* __restrict__ counter)
{
  __shared__ int part[1024];
  int t = threadIdx.x;
  int base = t * 8;
  int local[8];
  int s = 0;
#pragma unroll
  for (int i = 0; i < 8; i++){ local[i] = s; s += hist[base + i]; }
  part[t] = s;
  __syncthreads();
  for (int off = 1; off < 1024; off <<= 1){
    int v = (t >= off) ? part[t - off] : 0;
    __syncthreads();
    part[t] += v;
    __syncthreads();
  }
  int pre = (t == 0) ? 0 : part[t - 1];
#pragma unroll
  for (int i = 0; i < 8; i++){
    int rp = pre + local[i];
    rowptr[base + i] = rp;
    counter[base + i] = rp;
  }
  if (t == 1023) rowptr[8192] = part[1023];
}

__global__ __launch_bounds__(256) void perm_k(const int* __restrict__ dst,
                                              int* __restrict__ counter,
                                              int* __restrict__ pos)
{
  int e = blockIdx.x * 256 + threadIdx.x;
  if (e < Ne) pos[e] = atomicAdd(&counter[dst[e]], 1);
}

__global__ __launch_bounds__(256) void sortidx_k(
  const int* __restrict__ dst, const int* __restrict__ srcI,
  const int* __restrict__ pos, int* __restrict__ dstS, int* __restrict__ srcS)
{
  int e = blockIdx.x * 256 + threadIdx.x;
  if (e < Ne){
    int p = pos[e];
    dstS[p] = dst[e];
    srcS[p] = srcI[e];
  }
}

// ---------------- BatchNorm over y[n][c] = lg[c]*S[n][c] + cnt[n]*lb[c] ------
__global__ __launch_bounds__(256) void bn_stats_f(
  const float* __restrict__ S, const int* __restrict__ rowptr,
  const float* __restrict__ lg, const float* __restrict__ lb,
  float* __restrict__ sums)
{
  int c  = threadIdx.x;
  int r0 = blockIdx.x * 128;
  float gc = lg[c], bc = lb[c];
  float s1 = 0.f, s2 = 0.f;
  for (int r = r0; r < r0 + 128; r++){
    float cnt = (float)(rowptr[r + 1] - rowptr[r]);
    float y = gc * S[(long)r * Cc + c] + cnt * bc;
    s1 += y; s2 += y * y;
  }
  atomicAdd(&sums[c],      s1);
  atomicAdd(&sums[Cc + c], s2);
}

// layer 2 (no pddc): x = softplus(x + BN(y))
__global__ __launch_bounds__(256) void bn_apply_softplus_f(
  float* __restrict__ x, bf16* __restrict__ xbf,
  const float* __restrict__ S, const int* __restrict__ rowptr,
  const float* __restrict__ lg, const float* __restrict__ lb,
  const float* __restrict__ sums,
  const float* __restrict__ g, const float* __restrict__ b)
{
  long r = blockIdx.x;
  int c = threadIdx.x;
  float cnt = (float)(rowptr[r + 1] - rowptr[r]);
  float y = lg[c] * S[r * Cc + c] + cnt * lb[c];
  float m    = sums[c] * (1.0f / Nn);
  float var  = sums[Cc + c] * (1.0f / Nn) - m * m;
  float rstd = rsqrtf(var + 1e-5f);
  float bn = (y - m) * rstd * g[c] + b[c];
  float v  = x[r * Cc + c] + bn;
  float sp = (v > 0.f) ? v + log1pf(__expf(-v)) : log1pf(__expf(v));
  x[r * Cc + c] = sp;
  xbf[r * Cc + c] = __float2bfloat16(sp);
}

// layers 0-1: fused apply + p += sp + p-stats -> sums2 (16 rows/block, 512 blocks)
__global__ __launch_bounds__(256) void bn_apply_padd_k(
  float* __restrict__ x, bf16* __restrict__ xbf, float* __restrict__ p,
  const float* __restrict__ S, const int* __restrict__ rowptr,
  const float* __restrict__ lg, const float* __restrict__ lb,
  const float* __restrict__ sums,
  const float* __restrict__ g, const float* __restrict__ b,
  float* __restrict__ sums2)
{
  int c  = threadIdx.x;
  int r0 = blockIdx.x * 16;
  float gc = lg[c], bc = lb[c];
  float m    = sums[c] * (1.0f / Nn);
  float var  = sums[Cc + c] * (1.0f / Nn) - m * m;
  float rstd = rsqrtf(var + 1e-5f);
  float bg = g[c], bb2 = b[c];
  float s1 = 0.f, s2 = 0.f;
  for (int r = r0; r < r0 + 16; r++){
    long idx = (long)r * Cc + c;
    float cnt = (float)(rowptr[r + 1] - rowptr[r]);
    float y = gc * S[idx] + cnt * bc;
    float bn = (y - m) * rstd * bg + bb2;
    float v  = x[idx] + bn;
    float sp = (v > 0.f) ? v + log1pf(__expf(-v)) : log1pf(__expf(v));
    x[idx] = sp;
    xbf[idx] = __float2bfloat16(sp);
    float pv = p[idx] + sp;
    p[idx] = pv;
    s1 += pv; s2 += pv * pv;
  }
  atomicAdd(&sums2[c],      s1);
  atomicAdd(&sums2[Cc + c], s2);
}

// adj_bf = bf16(p*S + T), S/T computed inline from sums2
__global__ __launch_bounds__(256) void bnaff_st_k(
  const float* __restrict__ p, const float* __restrict__ sums,
  const float* __restrict__ g, const float* __restrict__ b,
  bf16* __restrict__ out)
{
  long r = blockIdx.x;
  int c = threadIdx.x;
  float m    = sums[c] * (1.0f / Nn);
  float var  = sums[Cc + c] * (1.0f / Nn) - m * m;
  float rstd = rsqrtf(var + 1e-5f);
  float S = g[c] * rstd;
  float T = b[c] - m * rstd * g[c];
  out[r * 256 + c] = __float2bfloat16(p[r * 256 + c] * S + T);
}

__global__ __launch_bounds__(256) void pool_k(
  const float* __restrict__ x, const int* __restrict__ batch,
  float* __restrict__ pooled, float* __restrict__ counts)
{
  long r = blockIdx.x;
  int c = threadIdx.x;
  long b = batch[r];
  atomicAdd(&pooled[b * Cc + c], x[r * Cc + c]);
  if (c == 0) atomicAdd(&counts[b], 1.0f);
}

__global__ __launch_bounds__(256) void pooldiv_k(
  float* __restrict__ pooled, const float* __restrict__ counts)
{
  int b = blockIdx.x;
  int c = threadIdx.x;
  float cnt = counts[b];
  if (cnt < 1.f) cnt = 1.f;
  pooled[b * Cc + c] /= cnt;
}

__global__ __launch_bounds__(256) void out_k(
  const float* __restrict__ cf, const float* __restrict__ ow,
  const float* __restrict__ ob, float* __restrict__ out)
{
  __shared__ float sm[8];
  int b = blockIdx.x;
  int c = threadIdx.x;
  float v = cf[(long)b * Cc + c] * ow[c];
  float dummy = 0.f;
  block_reduce_2(v, dummy, sm);
  if (c == 0) out[b] = v + ob[0];
}

// ---------------- host helpers ----------------
static inline void launch_gemm(hipStream_t st,
  const void* A0, int K0, int ld0,
  long M, int Nout, const float* W, const float* bias,
  const float* res, int ldRes, void* Cout, int outDt, int act)
{
  dim3 grid((unsigned)((M + 63) / 64), (unsigned)(Nout / 128));
  gemm_k<<<grid, dim3(256), 0, st>>>(
    A0, K0, ld0, M, Nout, W, bias, res, ldRes, Cout, outDt, act);
}

static inline void launch_mg(hipStream_t st, long M, int panels,
  const bf16* A, const bf16* Bpack, const float* bias,
  bf16* o0, bf16* o1, bf16* o2, bf16* o3, bf16* o4,
  float* fout, bf16* foutBf, int act, const int* outPerm,
  const bf16* gelAux = nullptr)
{
  dim3 grid((unsigned)panels, (unsigned)(M / 64));
  mg_k<<<grid, dim3(256), 0, st>>>(A, Bpack, bias, o0, o1, o2, o3, o4,
                                   fout, foutBf, act, outPerm, gelAux);
}

extern "C" void kernel_launch(void* const* d_in, const int* in_sizes, int n_in,
                              void* d_out, int out_size, void* d_ws, size_t ws_size,
                              hipStream_t stream)
{
  (void)in_sizes; (void)n_in; (void)out_size; (void)ws_size;

  const float* node       = (const float*)d_in[0];
  const int*   edge_index = (const int*)  d_in[1];
  const float* edge_attr  = (const float*)d_in[2];
  const float* pdd        = (const float*)d_in[3];
  const int*   batch      = (const int*)  d_in[4];
  const float* atom_W1 = (const float*)d_in[5];
  const float* atom_b1 = (const float*)d_in[6];
  const float* atom_W2 = (const float*)d_in[7];
  const float* atom_b2 = (const float*)d_in[8];
  const float* edge_W  = (const float*)d_in[9];
  const float* edge_b  = (const float*)d_in[10];
  const float* pdd_W   = (const float*)d_in[11];
  const float* pdd_b   = (const float*)d_in[12];
  const float* conv_Wq = (const float*)d_in[13];
  const float* conv_bq = (const float*)d_in[14];
  const float* conv_Wk = (const float*)d_in[15];
  const float* conv_bk = (const float*)d_in[16];
  const float* conv_Wv = (const float*)d_in[17];
  const float* conv_bv = (const float*)d_in[18];
  const float* conv_We = (const float*)d_in[19];
  const float* conv_be = (const float*)d_in[20];
  const float* conv_Wku = (const float*)d_in[21];
  const float* conv_bku = (const float*)d_in[22];
  const float* conv_Wmu = (const float*)d_in[23];
  const float* conv_bmu = (const float*)d_in[24];
  const float* conv_Wm  = (const float*)d_in[25];
  const float* conv_bm  = (const float*)d_in[26];
  const float* ln_m_g = (const float*)d_in[27];
  const float* ln_m_b = (const float*)d_in[28];
  const float* ln_a_g = (const float*)d_in[29];
  const float* ln_a_b = (const float*)d_in[30];
  const float* bn_g   = (const float*)d_in[31];
  const float* bn_b   = (const float*)d_in[32];
  const float* pddc_W1 = (const float*)d_in[33];
  const float* pddc_b1 = (const float*)d_in[34];
  const float* pddc_W2 = (const float*)d_in[35];
  const float* pddc_b2 = (const float*)d_in[36];
  const float* pddc_W3 = (const float*)d_in[37];
  const float* pddc_b3 = (const float*)d_in[38];
  const float* pddc_bn_g = (const float*)d_in[39];
  const float* pddc_bn_b = (const float*)d_in[40];
  const float* fc_W  = (const float*)d_in[41];
  const float* fc_b  = (const float*)d_in[42];
  const float* out_W = (const float*)d_in[43];
  const float* out_b = (const float*)d_in[44];

  const int* src = edge_index;
  const int* dst = edge_index + Ne;

  // ---- workspace carve-up (~248 MB) ----
  char* ws = (char*)d_ws;
  size_t off = 0;
  auto alloc = [&](size_t nbytes) -> char* {
    char* ptr = ws + off;
    off += (nbytes + 255) & ~(size_t)255;
    return ptr;
  };
  bf16*  e_in = (bf16*) alloc((size_t)Ne * Cc * 2);   // dst-sorted
  bf16*  bufB = (bf16*) alloc((size_t)Ne * Cc * 2);   // pddc ub scratch
  bf16*  bufC = (bf16*) alloc((size_t)Ne * Cc * 2);   // embed scratch | pddc a2a,a2b
  float* x    = (float*)alloc((size_t)Nn * Cc * 4);
  float* p    = (float*)alloc((size_t)Nn * Cc * 4);
  float* agg  = (float*)alloc((size_t)Nn * Cc * 4);
  bf16*  x_bf  = (bf16*)alloc((size_t)Nn * Cc * 2);
  bf16*  q_bf  = (bf16*)alloc((size_t)Nn * Cc * 2);
  bf16*  kp1   = (bf16*)alloc((size_t)Nn * Cc * 2);
  bf16*  kp2   = (bf16*)alloc((size_t)Nn * Cc * 2);
  bf16*  vp1   = (bf16*)alloc((size_t)Nn * Cc * 2);
  bf16*  vp2   = (bf16*)alloc((size_t)Nn * Cc * 2);
  bf16*  WpN5  = (bf16*)alloc((size_t)3 * 5 * 65536 * 2);
  bf16*  WpEdge= (bf16*)alloc((size_t)3 * 2 * 65536 * 2);
  bf16*  WpM   = (bf16*)alloc((size_t)3 * 65536 * 2);
  bf16*  WpE   = (bf16*)alloc((size_t)65536 * 2);
  bf16*  WpP1  = (bf16*)alloc((size_t)2 * 2 * 65536 * 2);
  bf16*  WpP2  = (bf16*)alloc((size_t)2 * 65536 * 2);
  bf16*  WpP3  = (bf16*)alloc((size_t)2 * 65536 * 2);
  float* nodeb = (float*)alloc((size_t)3 * 1280 * 4);
  float* b_edge= (float*)alloc((size_t)3 * 512 * 4);
  int*   hist    = (int*)alloc((size_t)8192 * 4);
  int*   rowptr  = (int*)alloc((size_t)8193 * 4);
  int*   counter = (int*)alloc((size_t)8192 * 4);
  int*   pos     = (int*)alloc((size_t)Ne * 4);
  int*   dstS    = (int*)alloc((size_t)Ne * 4);
  int*   srcS    = (int*)alloc((size_t)Ne * 4);
  float* pooled = (float*)alloc((size_t)Bb * Cc * 4);
  float* counts = (float*)alloc((size_t)Bb * 4);
  float* cf     = (float*)alloc((size_t)Bb * Cc * 4);
  float* bnsum  = (float*)alloc(4 * Cc * 4);   // [0,512): layer BN; [512,1024): pddc BN

  // embedding-time aliases inside bufC
  float* hidden = (float*)(bufC + (size_t)1024 * 1024);
  // pddc-time aliases
  bf16* a2a = bufC;
  bf16* a2b = bufC + (size_t)Nn * Cc;
  bf16* ub  = bufB;

  // ---- segment structures ----
  zero_i_k<<<dim3(8), dim3(256), 0, stream>>>(hist, 8192);
  hist_k<<<dim3(Ne / 256), dim3(256), 0, stream>>>(dst, hist);
  scan_k<<<dim3(1), dim3(1024), 0, stream>>>(hist, rowptr, counter);
  perm_k<<<dim3(Ne / 256), dim3(256), 0, stream>>>(dst, counter, pos);
  sortidx_k<<<dim3(Ne / 256), dim3(256), 0, stream>>>(dst, src, pos, dstS, srcS);

  // ---- prep: batched folds + packs + bias folds ----
  fold_k<<<dim3(4, 2, 18), dim3(256), 0, stream>>>(
    conv_Wk, conv_Wv, conv_We, conv_Wku, conv_Wmu, WpN5, WpEdge);
  pack_qm_k<<<dim3(256, 6), dim3(256), 0, stream>>>(conv_Wq, conv_Wm, WpN5, WpM);
  fuse_bias_all_k<<<dim3(6), dim3(256), 0, stream>>>(
    conv_bku, conv_bmu, conv_be, conv_bk, conv_bv, conv_Wku, conv_Wmu, b_edge);
  nodeb_all_k<<<dim3(15), dim3(256), 0, stream>>>(conv_bq, nodeb);
  pack_b2_k<<<dim3(256, 1), dim3(256), 0, stream>>>(edge_W, 256, WpE);
  for (int j = 0; j < 2; j++){
    pack_b2_k<<<dim3(256, 2), dim3(256), 0, stream>>>(
      pddc_W1 + (size_t)j * 256 * 512, 512, WpP1 + (size_t)j * 2 * 65536);
    pack_b2_k<<<dim3(256, 1), dim3(256), 0, stream>>>(
      pddc_W2 + (size_t)j * 65536, 256, WpP2 + (size_t)j * 65536);
    pack_b2_k<<<dim3(256, 1), dim3(256), 0, stream>>>(
      pddc_W3 + (size_t)j * 65536, 256, WpP3 + (size_t)j * 65536);
  }

  // ---- embeddings ----
  launch_gemm(stream, node, 92, 92, Nn, Cc, atom_W1, atom_b1,
              nullptr, 0, hidden, 0, 1);
  launch_gemm(stream, hidden, 256, 256, Nn, Cc, atom_W2, atom_b2,
              nullptr, 0, x, 0, 0);
  f2bf_k<<<dim3(512), dim3(256), 0, stream>>>(x_bf, x, (long)Nn * Cc);
  launch_gemm(stream, pdd, 51, 51, Nn, Cc, pdd_W, pdd_b,
              nullptr, 0, p, 0, 0);
  // e_in = silu(rbf(d(edge_attr)) @ edge_W + edge_b), sorted out
  rbf_mg_k<<<dim3(Ne / 64), dim3(256), 0, stream>>>(edge_attr, WpE, edge_b, e_in, pos);

  for (int i = 0; i < 3; i++){
    // q, kp1, kp2, vp1, vp2 (5-panel)
    launch_mg(stream, Nn, 5, x_bf, WpN5 + (size_t)i * 5 * 65536, nodeb + i * 1280,
              q_bf, kp1, kp2, vp1, vp2, nullptr, nullptr, 0, nullptr);
    // zero agg + bnsum(1024) in one dispatch
    zero2_k<<<dim3(1024), dim3(256), 0, stream>>>(agg, (long)Nn * Cc, bnsum, 1024);
    conv_edge_k<<<dim3(Ne / 32), dim3(256), 0, stream>>>(
      e_in, WpEdge + (size_t)i * 2 * 65536, b_edge + i * 512,
      WpM + (size_t)i * 65536, conv_bm + i * 256,
      q_bf, kp1, kp2, vp1, vp2, dstS, srcS,
      ln_a_g + i * 256, ln_a_b + i * 256, agg);
    bn_stats_f<<<dim3(Nn / 128), dim3(256), 0, stream>>>(agg, rowptr,
              ln_m_g + i * 256, ln_m_b + i * 256, bnsum);

    if (i < 2){
      int j = i;
      // x = softplus(x + BN(y)); p += x; p-stats -> bnsum[512:]  (512 blocks)
      bn_apply_padd_k<<<dim3(Nn / 16), dim3(256), 0, stream>>>(
              x, x_bf, p, agg, rowptr,
              ln_m_g + i * 256, ln_m_b + i * 256, bnsum,
              bn_g + i * 256, bn_b + i * 256, bnsum + 512);
      bnaff_st_k<<<dim3(Nn), dim3(256), 0, stream>>>(p, bnsum + 512,
              pddc_bn_g + j * 256, pddc_bn_b + j * 256, x_bf);
      launch_mg(stream, Nn, 2, x_bf, WpP1 + (size_t)j * 2 * 65536, pddc_b1 + j * 512,
                a2a, a2b, nullptr, nullptr, nullptr, nullptr, nullptr, 0, nullptr);
      // u = (a2a@W2 + b2) * gelu(a2b)   (fused epilogue)
      launch_mg(stream, Nn, 1, a2a, WpP2 + (size_t)j * 65536, pddc_b2 + j * 256,
                ub, nullptr, nullptr, nullptr, nullptr, nullptr, nullptr, 0, nullptr,
                a2b);
      // x = u @ W3 + b3 + x  (fp32 in-place, bf16 shadow refresh)
      launch_mg(stream, Nn, 1, ub, WpP3 + (size_t)j * 65536, pddc_b3 + j * 256,
                nullptr, nullptr, nullptr, nullptr, nullptr, x, x_bf, 0, nullptr);
    } else {
      bn_apply_softplus_f<<<dim3(Nn), dim3(256), 0, stream>>>(x, x_bf, agg, rowptr,
              ln_m_g + i * 256, ln_m_b + i * 256, bnsum,
              bn_g + i * 256, bn_b + i * 256);
    }
  }

  // ---- pooling + head ----
  zero2_k<<<dim3(64), dim3(256), 0, stream>>>(pooled, (long)Bb * Cc, counts, Bb);
  pool_k<<<dim3(Nn), dim3(256), 0, stream>>>(x, batch, pooled, counts);
  pooldiv_k<<<dim3(Bb), dim3(256), 0, stream>>>(pooled, counts);
  launch_gemm(stream, pooled, 256, 256, Bb, Cc, fc_W, fc_b,
              pooled, Cc, cf, 0, 1);
  out_k<<<dim3(Bb), dim3(256), 0, stream>>>(cf, out_W, out_b, (float*)d_out);
}